// Round 1
// baseline (197.714 us; speedup 1.0000x reference)
//
#include <hip/hip_runtime.h>
#include <math.h>

#define HID 1024
#define NHEADS 16
#define NTILES 36
#define HEADSZ (36*128*64)
#define LOG2E 1.4426950408889634f
#define PLSTRIDE 73728   // 16*36*128

typedef unsigned short u16;
typedef unsigned int u32;
typedef __attribute__((ext_vector_type(8))) u16 ushort8v;
typedef __attribute__((ext_vector_type(8))) __bf16 bf16x8;
typedef __attribute__((ext_vector_type(16))) float f32x16;
typedef __attribute__((ext_vector_type(4))) u32 u32x4;

__device__ __forceinline__ u32 cvt_pk_bf16(float lo, float hi) {
  u32 r;
  asm("v_cvt_pk_bf16_f32 %0, %1, %2" : "=v"(r) : "v"(lo), "v"(hi));
  return r;
}
__device__ __forceinline__ void permlane32_swap(u32 &a, u32 &b) {
  asm volatile("v_permlane32_swap_b32 %0, %1" : "+v"(a), "+v"(b));
}
__device__ __forceinline__ void gld_lds16(const void* g, void* l) {
  __builtin_amdgcn_global_load_lds((const __attribute__((address_space(1))) u32*)g,
                                   (__attribute__((address_space(3))) u32*)l, 16, 0, 0);
}
__device__ __forceinline__ f32x16 mfma32(bf16x8 a, bf16x8 b, f32x16 c) {
  return __builtin_amdgcn_mfma_f32_32x32x16_bf16(a, b, c, 0, 0, 0);
}
__device__ __forceinline__ u16 bf16r(float x) {
  u32 b = __builtin_bit_cast(u32, x);
  b += 0x7fff + ((b >> 16) & 1);
  return (u16)(b >> 16);
}
__device__ __forceinline__ float bf2f(u16 v) {
  return __builtin_bit_cast(float, (u32)v << 16);
}

// ---------------- cast fp32 -> bf16 (5 arrays in one launch) ----------------
struct CastJob { const float* src[5]; u16* dst[5]; int n[5]; };

__global__ __launch_bounds__(256)
void cast_bf16(CastJob j) {
  const int w = blockIdx.y;
  const int n = j.n[w];
  const int i = (blockIdx.x * 256 + threadIdx.x) * 8;
  if (i >= n) return;
  const float4 v0 = *reinterpret_cast<const float4*>(j.src[w] + i);
  const float4 v1 = *reinterpret_cast<const float4*>(j.src[w] + i + 4);
  u32x4 o;
  o.x = cvt_pk_bf16(v0.x, v0.y);
  o.y = cvt_pk_bf16(v0.z, v0.w);
  o.z = cvt_pk_bf16(v1.x, v1.y);
  o.w = cvt_pk_bf16(v1.z, v1.w);
  *reinterpret_cast<u32x4*>(j.dst[w] + i) = o;
}

// ---------------- bf16 MFMA GEMM: C = A @ B^T ----------------
// M iterated in TILEIZED order (blockIdx.y = attention tile, 128 rows).
// AMODE 0: A bf16 row-major [4608][1024].  AMODE 1: A bf16 tileized.
// CMODE 0: C fp32 row-major.               CMODE 1: C bf16 tileized.
// QKV: B/C span q|k|v; heads >=32 (the V section) are written TRANSPOSED
//      ([head][tile][dh][within]) so no separate transpose pass is needed.
// DBUF: double-buffered LDS (64KB) vs single-buffer (32KB).
template<int AMODE, int CMODE, bool QKV, bool DBUF>
__global__ __launch_bounds__(256)
void gemm_mfma(const u16* __restrict__ A, const u16* __restrict__ B,
               void* __restrict__ Cv, float alpha)
{
    __shared__ __align__(16) u16 sm[DBUF ? 2 : 1][2][8192];

    const int tid = threadIdx.x;
    const int wv = tid >> 6, l = tid & 63;
    const int l31 = l & 31, hi = l >> 5;
    const int wm = wv >> 1, wn = wv & 1;
    const int by = blockIdx.y;
    const int n0 = blockIdx.x * 128;
    const float av = (QKV && n0 >= 1024) ? 1.0f : alpha;

    const int tt = by / 9, rem = by % 9, th = rem / 3, tw = rem % 3;
    const int tilebase = tt * 1152 + th * 192 + tw * 8;

    const int lrow = l >> 3;
    const int lslot = l & 7;
    const int sg = (lslot ^ lrow) * 8;
    const u16* aptr[4];
    const u16* bptr[4];
#pragma unroll
    for (int i = 0; i < 4; ++i) {
        const int row = (wv * 4 + i) * 8 + lrow;
        if (AMODE == 0) {
            const int s = tilebase + (row >> 6) * 576 + ((row >> 3) & 7) * 24 + (row & 7);
            aptr[i] = A + (size_t)s * HID + sg;
        } else {
            aptr[i] = A + (size_t)(by * 128 + row) * 64 + sg;
        }
        bptr[i] = B + (size_t)(n0 + row) * HID + sg;
    }

    auto stage = [&](int buf, int kc) {
#pragma unroll
        for (int i = 0; i < 4; ++i) {
            const u16* ga = (AMODE == 0) ? (aptr[i] + kc)
                                         : (aptr[i] + (size_t)(kc >> 6) * HEADSZ);
            gld_lds16(ga, &sm[buf][0][(wv * 4 + i) * 512]);
            gld_lds16(bptr[i] + kc, &sm[buf][1][(wv * 4 + i) * 512]);
        }
    };

    f32x16 acc[2][2];
#pragma unroll
    for (int mb = 0; mb < 2; ++mb)
#pragma unroll
        for (int nb = 0; nb < 2; ++nb)
#pragma unroll
            for (int i = 0; i < 16; ++i) acc[mb][nb][i] = 0.f;

    auto compute = [&](int buf) {
        __builtin_amdgcn_s_setprio(1);
#pragma unroll
        for (int kk = 0; kk < 4; ++kk) {
            bf16x8 af[2], bfr[2];
#pragma unroll
            for (int mb = 0; mb < 2; ++mb) {
                const int row = wm * 64 + mb * 32 + l31;
                af[mb] = *reinterpret_cast<const bf16x8*>(
                    &sm[buf][0][row * 64 + (((kk * 2 + hi) ^ (row & 7)) * 8)]);
            }
#pragma unroll
            for (int nb = 0; nb < 2; ++nb) {
                const int row = wn * 64 + nb * 32 + l31;
                bfr[nb] = *reinterpret_cast<const bf16x8*>(
                    &sm[buf][1][row * 64 + (((kk * 2 + hi) ^ (row & 7)) * 8)]);
            }
#pragma unroll
            for (int mb = 0; mb < 2; ++mb)
#pragma unroll
                for (int nb = 0; nb < 2; ++nb)
                    acc[mb][nb] = mfma32(af[mb], bfr[nb], acc[mb][nb]);
        }
        __builtin_amdgcn_s_setprio(0);
    };

    if (DBUF) {
        stage(0, 0);
        __syncthreads();
        int cur = 0;
        for (int kc = 0; kc < HID; kc += 64) {
            if (kc + 64 < HID) stage(cur ^ 1, kc + 64);
            compute(cur);
            __syncthreads();
            cur ^= 1;
        }
    } else {
        for (int kc = 0; kc < HID; kc += 64) {
            __syncthreads();
            stage(0, kc);
            __syncthreads();
            compute(0);
        }
    }

    if (CMODE == 0) {
        float* C = (float*)Cv;
#pragma unroll
        for (int mb = 0; mb < 2; ++mb)
#pragma unroll
            for (int r = 0; r < 16; ++r) {
                const int m = wm * 64 + mb * 32 + (r & 3) + 8 * (r >> 2) + 4 * hi;
                const int s = tilebase + (m >> 6) * 576 + ((m >> 3) & 7) * 24 + (m & 7);
#pragma unroll
                for (int nb = 0; nb < 2; ++nb) {
                    const int n = n0 + wn * 64 + nb * 32 + l31;
                    C[(size_t)s * HID + n] = acc[mb][nb][r] * av;
                }
            }
    } else {
        u16* C = (u16*)Cv;
#pragma unroll
        for (int mb = 0; mb < 2; ++mb)
#pragma unroll
            for (int rq = 0; rq < 4; ++rq) {
                const int mbase = wm * 64 + mb * 32 + 8 * rq + 4 * hi;
#pragma unroll
                for (int nb = 0; nb < 2; ++nb) {
                    const int n = n0 + wn * 64 + nb * 32 + l31;
                    const int head = n >> 6, dh = n & 63;
                    if (QKV && head >= 32) {
                        // V: write transposed [head][tile][dh][within]
                        u32 w0 = cvt_pk_bf16(acc[mb][nb][rq * 4 + 0], acc[mb][nb][rq * 4 + 1]);
                        u32 w1 = cvt_pk_bf16(acc[mb][nb][rq * 4 + 2], acc[mb][nb][rq * 4 + 3]);
                        *reinterpret_cast<uint2*>(C + (size_t)head * HEADSZ +
                            (size_t)by * 8192 + dh * 128 + mbase) = make_uint2(w0, w1);
                    } else {
#pragma unroll
                        for (int j = 0; j < 4; ++j) {
                            const int m = mbase + j;
                            C[(size_t)head * HEADSZ + (size_t)(by * 128 + m) * 64 + dh] =
                                bf16r(acc[mb][nb][rq * 4 + j] * av);
                        }
                    }
                }
            }
    }
}

// attention: 1152 blocks = (head, q-tile, key-parity); 4 waves = 2qw x 2kw.
// Each wave owns 64 q-rows (qw) x 32 of the 64 staged keys (kw): every
// K/V LDS fragment read feeds TWO MFMAs (2 q-blocks in registers), halving
// LDS-port traffic vs the 32q-per-wave layout (the measured bottleneck).
// kw partials (accO, lsum) merge once at the end through the LDS buffer.
// No-max softmax -> partials merge by pure addition in merge_attn.
// XCD-swizzled blockIdx: each XCD owns 2 heads (K/V fit its 4MB L2).
__global__ __launch_bounds__(256, 3)
void attn_mfma(const u16* __restrict__ Q, const u16* __restrict__ K,
               const u16* __restrict__ Vt, u16* __restrict__ pO0,
               u16* __restrict__ pO1, float* __restrict__ pl)
{
    __shared__ u16 sm[2][2][4096];   // [buf][K=0 / V=1][64 x 64] = 32 KB
    __shared__ float lsl[2][2][32];  // [qw][qb][q31] kw=1 lsum handoff

    const int tid = threadIdx.x;
    const int wave = tid >> 6;
    const int lane = tid & 63;
    const int l31 = lane & 31;
    const int hi  = lane >> 5;
    const int qw  = wave & 1;
    const int kw  = wave >> 1;

    // XCD-aware bijective swizzle: 1152 = 8 * 144
    const int logical = (blockIdx.x & 7) * 144 + (blockIdx.x >> 3);
    const int p  = logical & 1;
    const int bt = logical >> 1;       // head*36 + tile
    const int tl = bt % NTILES;
    const int hd = bt / NTILES;
    const size_t headbase = (size_t)hd * HEADSZ;

    const u16* Qg = Q + headbase + (size_t)tl * 8192;
    const u16* Kh = K + headbase;
    const u16* Vh = Vt + headbase;

    // 64 q-rows per wave, in registers: [qb][ks]
    bf16x8 qf[2][4];
#pragma unroll
    for (int qb = 0; qb < 2; ++qb) {
        const u16* qrow = Qg + (qw * 64 + qb * 32 + l31) * 64 + hi * 8;
#pragma unroll
        for (int ks = 0; ks < 4; ++ks)
            qf[qb][ks] = *reinterpret_cast<const bf16x8*>(qrow + ks * 16);
    }

    const int base_t = (min(max(tl / 9, 1), 2) - 1) * 9;

    const int srow = lane >> 3;   // 0..7
    const int slot = lane & 7;

    auto stage = [&](int i, int bi) {
        const int kt = base_t + i;
        const u16* Kg = Kh + (size_t)kt * 8192 + p * 4096;
        const u16* Vg = Vh + (size_t)kt * 8192 + p * 64;
        u16* dk = &sm[bi][0][0];
        u16* dv = &sm[bi][1][0];
#pragma unroll
        for (int q = 0; q < 2; ++q) {
            const int seg = wave * 2 + q;
            const int key = seg * 8 + srow;
            gld_lds16(Kg + key * 64 + ((slot ^ (key & 7)) * 8), dk + seg * 512);
            const int dh = seg * 8 + srow;
            gld_lds16(Vg + dh * 128 + ((slot ^ (dh & 7)) * 8), dv + seg * 512);
        }
    };

    f32x16 accO[2][2];  // [dhb][qb]: 64 dh x 64 q partial (this wave's keys)
#pragma unroll
    for (int dhb = 0; dhb < 2; ++dhb)
#pragma unroll
        for (int qb = 0; qb < 2; ++qb)
#pragma unroll
            for (int i = 0; i < 16; ++i) accO[dhb][qb][i] = 0.f;
    float lsum[2] = {0.f, 0.f};

    stage(0, 0);
    __syncthreads();

    const int kr = kw * 32 + l31;

    for (int i = 0; i < 27; ++i) {
        const int cur = i & 1;
        if (i + 1 < 27) stage(i + 1, cur ^ 1);
        const u16* Ksb = &sm[cur][0][0];
        const u16* Vsb = &sm[cur][1][0];

        // K fragments for this wave's 32 keys: read ONCE, used by both qb.
        bf16x8 af[4];
#pragma unroll
        for (int ks = 0; ks < 4; ++ks)
            af[ks] = *reinterpret_cast<const bf16x8*>(
                Ksb + kr * 64 + (((2 * ks + hi) ^ (kr & 7)) * 8));

        bf16x8 pb[2][2];
#pragma unroll
        for (int qb = 0; qb < 2; ++qb) {
            f32x16 s;
#pragma unroll
            for (int i2 = 0; i2 < 16; ++i2) s[i2] = 0.f;
            __builtin_amdgcn_s_setprio(1);
#pragma unroll
            for (int ks = 0; ks < 4; ++ks)
                s = mfma32(af[ks], qf[qb][ks], s);
            __builtin_amdgcn_s_setprio(0);

            // plain exp2 (scores pre-scaled by log2e/8 in Q; bounded, no max)
#pragma unroll
            for (int i2 = 0; i2 < 16; ++i2) s[i2] = __builtin_amdgcn_exp2f(s[i2]);

            float ps = 0.f;
#pragma unroll
            for (int i2 = 0; i2 < 16; ++i2) ps += s[i2];
            lsum[qb] += ps;

            // pack P -> 2 bf16 B-frags (this wave's 32 keys x 32 q)
            u32 a0 = cvt_pk_bf16(s[0], s[1]);
            u32 a1 = cvt_pk_bf16(s[2], s[3]);
            u32 b0 = cvt_pk_bf16(s[4], s[5]);
            u32 b1 = cvt_pk_bf16(s[6], s[7]);
            permlane32_swap(a0, b0);
            permlane32_swap(a1, b1);
            u32x4 w; w.x = a0; w.y = a1; w.z = b0; w.w = b1;
            pb[qb][0] = __builtin_bit_cast(bf16x8, w);
            u32 c0 = cvt_pk_bf16(s[8], s[9]);
            u32 c1 = cvt_pk_bf16(s[10], s[11]);
            u32 d0 = cvt_pk_bf16(s[12], s[13]);
            u32 d1 = cvt_pk_bf16(s[14], s[15]);
            permlane32_swap(c0, d0);
            permlane32_swap(c1, d1);
            u32x4 w2; w2.x = c0; w2.y = c1; w2.z = d0; w2.w = d1;
            pb[qb][1] = __builtin_bit_cast(bf16x8, w2);
        }

        // PV: each V fragment read feeds both qb accumulators.
        __builtin_amdgcn_s_setprio(1);
#pragma unroll
        for (int k2 = 0; k2 < 2; ++k2) {
            const int sg2 = kw * 4 + k2 * 2 + hi;
            bf16x8 v0 = *reinterpret_cast<const bf16x8*>(
                Vsb + l31 * 64 + ((sg2 ^ (l31 & 7)) * 8));
            bf16x8 v1 = *reinterpret_cast<const bf16x8*>(
                Vsb + (32 + l31) * 64 + ((sg2 ^ ((32 + l31) & 7)) * 8));
            accO[0][0] = mfma32(v0, pb[0][k2], accO[0][0]);
            accO[1][0] = mfma32(v1, pb[0][k2], accO[1][0]);
            accO[0][1] = mfma32(v0, pb[1][k2], accO[0][1]);
            accO[1][1] = mfma32(v1, pb[1][k2], accO[1][1]);
        }
        __builtin_amdgcn_s_setprio(0);
        __syncthreads();
    }

    lsum[0] += __shfl_xor(lsum[0], 32);
    lsum[1] += __shfl_xor(lsum[1], 32);

    // cross-kw merge through LDS (loop is done with sm; last sync passed).
    // layout: [qw 2][chunk 16][lane 64][float4] -> 16B/lane stride, no conflicts
    float* fs = reinterpret_cast<float*>(&sm[0][0][0]);
    if (kw == 1) {
#pragma unroll
        for (int dhb = 0; dhb < 2; ++dhb)
#pragma unroll
            for (int qb = 0; qb < 2; ++qb)
#pragma unroll
                for (int r4 = 0; r4 < 4; ++r4) {
                    const int c = (dhb * 2 + qb) * 4 + r4;
                    float4 v = make_float4(accO[dhb][qb][4 * r4 + 0],
                                           accO[dhb][qb][4 * r4 + 1],
                                           accO[dhb][qb][4 * r4 + 2],
                                           accO[dhb][qb][4 * r4 + 3]);
                    *reinterpret_cast<float4*>(&fs[qw * 4096 + c * 256 + lane * 4]) = v;
                }
        if (hi == 0) { lsl[qw][0][l31] = lsum[0]; lsl[qw][1][l31] = lsum[1]; }
    }
    __syncthreads();
    if (kw == 0) {
#pragma unroll
        for (int dhb = 0; dhb < 2; ++dhb)
#pragma unroll
            for (int qb = 0; qb < 2; ++qb)
#pragma unroll
                for (int r4 = 0; r4 < 4; ++r4) {
                    const int c = (dhb * 2 + qb) * 4 + r4;
                    float4 v = *reinterpret_cast<const float4*>(
                        &fs[qw * 4096 + c * 256 + lane * 4]);
                    accO[dhb][qb][4 * r4 + 0] += v.x;
                    accO[dhb][qb][4 * r4 + 1] += v.y;
                    accO[dhb][qb][4 * r4 + 2] += v.z;
                    accO[dhb][qb][4 * r4 + 3] += v.w;
                }
        lsum[0] += lsl[qw][0][l31];
        lsum[1] += lsl[qw][1][l31];

        u16* Ob = (p ? pO1 : pO0) + ((size_t)(bt * 128 + qw * 64)) * 64;
#pragma unroll
        for (int qb = 0; qb < 2; ++qb)
#pragma unroll
            for (int dhb = 0; dhb < 2; ++dhb)
#pragma unroll
                for (int t = 0; t < 4; ++t) {
                    u32 w0 = cvt_pk_bf16(accO[dhb][qb][4 * t + 0], accO[dhb][qb][4 * t + 1]);
                    u32 w1 = cvt_pk_bf16(accO[dhb][qb][4 * t + 2], accO[dhb][qb][4 * t + 3]);
                    *reinterpret_cast<uint2*>(Ob + (qb * 32 + l31) * 64 +
                                              dhb * 32 + t * 8 + 4 * hi) = make_uint2(w0, w1);
                }
        if (hi == 0) {
            pl[p * PLSTRIDE + bt * 128 + qw * 64 + l31]      = lsum[0];
            pl[p * PLSTRIDE + bt * 128 + qw * 64 + 32 + l31] = lsum[1];
        }
    }
}

// merge the two key-parity partials: O = (pO0 + pO1) / (l0 + l1), bf16 tileized
__global__ __launch_bounds__(256)
void merge_attn(const u16* __restrict__ pO0, const u16* __restrict__ pO1,
                const float* __restrict__ pl, u16* __restrict__ O)
{
    const int b = blockIdx.x;          // head*36 + tile
    const int tid = threadIdx.x;
    const int row = tid >> 1;
    const int d0 = (tid & 1) * 32;
    const size_t rbase = ((size_t)b * 128 + row) * 64 + d0;
    const float inv = 1.f / (pl[b * 128 + row] + pl[PLSTRIDE + b * 128 + row]);
#pragma unroll
    for (int g = 0; g < 4; ++g) {
        ushort8v a = *reinterpret_cast<const ushort8v*>(pO0 + rbase + g * 8);
        ushort8v c = *reinterpret_cast<const ushort8v*>(pO1 + rbase + g * 8);
        u32 w[4];
#pragma unroll
        for (int h = 0; h < 4; ++h) {
            float f0 = (bf2f(a[2 * h])     + bf2f(c[2 * h]))     * inv;
            float f1 = (bf2f(a[2 * h + 1]) + bf2f(c[2 * h + 1])) * inv;
            w[h] = cvt_pk_bf16(f0, f1);
        }
        u32x4 st; st.x = w[0]; st.y = w[1]; st.z = w[2]; st.w = w[3];
        *reinterpret_cast<u32x4*>(O + rbase + g * 8) = st;
    }
}

extern "C" void kernel_launch(void* const* d_in, const int* in_sizes, int n_in,
                              void* d_out, int out_size, void* d_ws, size_t ws_size,
                              hipStream_t stream) {
    const float* hs = (const float*)d_in[0];
    const float* qw = (const float*)d_in[1];
    const float* kw = (const float*)d_in[2];
    const float* vw = (const float*)d_in[3];
    const float* ow = (const float*)d_in[4];
    float* out = (float*)d_out;

    const size_t TSZ = (size_t)NHEADS * HEADSZ;
    const size_t WSZ = (size_t)HID * HID;
    u16* hsb = (u16*)d_ws;      // reused as pO0 after the QKV GEMM consumes hs
    u16* wqb = hsb + TSZ;       // wq|wk|wv|wo contiguous
    u16* wkb = wqb + WSZ;
    u16* wvb = wkb + WSZ;
    u16* wob = wvb + WSZ;
    u16* qb  = wob + WSZ;       // q|k|vt contiguous (from fused QKV gemm)
    u16* kb  = qb + TSZ;
    u16* vt  = kb + TSZ;
    u16* pO0 = hsb;
    u16* pO1 = vt + TSZ;
    float* pl = (float*)(pO1 + TSZ);
    u16* aob = (u16*)(pl + 2 * PLSTRIDE);

    CastJob cj;
    cj.src[0] = hs; cj.dst[0] = hsb; cj.n[0] = (int)TSZ;
    cj.src[1] = qw; cj.dst[1] = wqb; cj.n[1] = (int)WSZ;
    cj.src[2] = kw; cj.dst[2] = wkb; cj.n[2] = (int)WSZ;
    cj.src[3] = vw; cj.dst[3] = wvb; cj.n[3] = (int)WSZ;
    cj.src[4] = ow; cj.dst[4] = wob; cj.n[4] = (int)WSZ;
    cast_bf16<<<dim3(2304, 5), 256, 0, stream>>>(cj);

    // fused QKV projection (V written pre-transposed)
    gemm_mfma<0, 1, true, true><<<dim3(24, 36), 256, 0, stream>>>(hsb, wqb, qb, 0.125f * LOG2E);
    attn_mfma<<<NHEADS * NTILES * 2, 256, 0, stream>>>(qb, kb, vt, pO0, pO1, pl);
    merge_attn<<<NHEADS * NTILES, 256, 0, stream>>>(pO0, pO1, pl, aob);
    gemm_mfma<1, 0, false, true><<<dim3(8, 36), 256, 0, stream>>>(aob, wob, out, 1.0f);
}

// Round 2
// 193.502 us; speedup vs baseline: 1.0218x; 1.0218x over previous
//
#include <hip/hip_runtime.h>
#include <math.h>

#define HID 1024
#define NHEADS 16
#define NTILES 36
#define HEADSZ (36*128*64)
#define LOG2E 1.4426950408889634f
#define PLSTRIDE 73728   // 16*36*128

typedef unsigned short u16;
typedef unsigned int u32;
typedef __attribute__((ext_vector_type(8))) u16 ushort8v;
typedef __attribute__((ext_vector_type(8))) __bf16 bf16x8;
typedef __attribute__((ext_vector_type(16))) float f32x16;
typedef __attribute__((ext_vector_type(4))) u32 u32x4;

__device__ __forceinline__ u32 cvt_pk_bf16(float lo, float hi) {
  u32 r;
  asm("v_cvt_pk_bf16_f32 %0, %1, %2" : "=v"(r) : "v"(lo), "v"(hi));
  return r;
}
__device__ __forceinline__ void permlane32_swap(u32 &a, u32 &b) {
  asm volatile("v_permlane32_swap_b32 %0, %1" : "+v"(a), "+v"(b));
}
__device__ __forceinline__ void gld_lds16(const void* g, void* l) {
  __builtin_amdgcn_global_load_lds((const __attribute__((address_space(1))) u32*)g,
                                   (__attribute__((address_space(3))) u32*)l, 16, 0, 0);
}
__device__ __forceinline__ f32x16 mfma32(bf16x8 a, bf16x8 b, f32x16 c) {
  return __builtin_amdgcn_mfma_f32_32x32x16_bf16(a, b, c, 0, 0, 0);
}
__device__ __forceinline__ u16 bf16r(float x) {
  u32 b = __builtin_bit_cast(u32, x);
  b += 0x7fff + ((b >> 16) & 1);
  return (u16)(b >> 16);
}
__device__ __forceinline__ float bf2f(u16 v) {
  return __builtin_bit_cast(float, (u32)v << 16);
}

// ---------------- cast fp32 -> bf16 (5 arrays in one launch) ----------------
struct CastJob { const float* src[5]; u16* dst[5]; int n[5]; };

__global__ __launch_bounds__(256)
void cast_bf16(CastJob j) {
  const int w = blockIdx.y;
  const int n = j.n[w];
  const int i = (blockIdx.x * 256 + threadIdx.x) * 8;
  if (i >= n) return;
  const float4 v0 = *reinterpret_cast<const float4*>(j.src[w] + i);
  const float4 v1 = *reinterpret_cast<const float4*>(j.src[w] + i + 4);
  u32x4 o;
  o.x = cvt_pk_bf16(v0.x, v0.y);
  o.y = cvt_pk_bf16(v0.z, v0.w);
  o.z = cvt_pk_bf16(v1.x, v1.y);
  o.w = cvt_pk_bf16(v1.z, v1.w);
  *reinterpret_cast<u32x4*>(j.dst[w] + i) = o;
}

// ---------------- bf16 MFMA GEMM: C = A @ B^T ----------------
// M iterated in TILEIZED order (blockIdx.y = attention tile, 128 rows).
// AMODE 0: A bf16 row-major [4608][1024].  AMODE 1: A bf16 tileized.
// CMODE 0: C fp32 row-major.               CMODE 1: C bf16 tileized.
// QKV: B/C span q|k|v; heads >=32 (the V section) are written TRANSPOSED
//      ([head][tile][dh][within]) so no separate transpose pass is needed.
// DBUF: double-buffered LDS (64KB) vs single-buffer (32KB).
template<int AMODE, int CMODE, bool QKV, bool DBUF>
__global__ __launch_bounds__(256)
void gemm_mfma(const u16* __restrict__ A, const u16* __restrict__ B,
               void* __restrict__ Cv, float alpha)
{
    __shared__ __align__(16) u16 sm[DBUF ? 2 : 1][2][8192];

    const int tid = threadIdx.x;
    const int wv = tid >> 6, l = tid & 63;
    const int l31 = l & 31, hi = l >> 5;
    const int wm = wv >> 1, wn = wv & 1;
    const int by = blockIdx.y;
    const int n0 = blockIdx.x * 128;
    const float av = (QKV && n0 >= 1024) ? 1.0f : alpha;

    const int tt = by / 9, rem = by % 9, th = rem / 3, tw = rem % 3;
    const int tilebase = tt * 1152 + th * 192 + tw * 8;

    const int lrow = l >> 3;
    const int lslot = l & 7;
    const int sg = (lslot ^ lrow) * 8;
    const u16* aptr[4];
    const u16* bptr[4];
#pragma unroll
    for (int i = 0; i < 4; ++i) {
        const int row = (wv * 4 + i) * 8 + lrow;
        if (AMODE == 0) {
            const int s = tilebase + (row >> 6) * 576 + ((row >> 3) & 7) * 24 + (row & 7);
            aptr[i] = A + (size_t)s * HID + sg;
        } else {
            aptr[i] = A + (size_t)(by * 128 + row) * 64 + sg;
        }
        bptr[i] = B + (size_t)(n0 + row) * HID + sg;
    }

    auto stage = [&](int buf, int kc) {
#pragma unroll
        for (int i = 0; i < 4; ++i) {
            const u16* ga = (AMODE == 0) ? (aptr[i] + kc)
                                         : (aptr[i] + (size_t)(kc >> 6) * HEADSZ);
            gld_lds16(ga, &sm[buf][0][(wv * 4 + i) * 512]);
            gld_lds16(bptr[i] + kc, &sm[buf][1][(wv * 4 + i) * 512]);
        }
    };

    f32x16 acc[2][2];
#pragma unroll
    for (int mb = 0; mb < 2; ++mb)
#pragma unroll
        for (int nb = 0; nb < 2; ++nb)
#pragma unroll
            for (int i = 0; i < 16; ++i) acc[mb][nb][i] = 0.f;

    auto compute = [&](int buf) {
        __builtin_amdgcn_s_setprio(1);
#pragma unroll
        for (int kk = 0; kk < 4; ++kk) {
            bf16x8 af[2], bfr[2];
#pragma unroll
            for (int mb = 0; mb < 2; ++mb) {
                const int row = wm * 64 + mb * 32 + l31;
                af[mb] = *reinterpret_cast<const bf16x8*>(
                    &sm[buf][0][row * 64 + (((kk * 2 + hi) ^ (row & 7)) * 8)]);
            }
#pragma unroll
            for (int nb = 0; nb < 2; ++nb) {
                const int row = wn * 64 + nb * 32 + l31;
                bfr[nb] = *reinterpret_cast<const bf16x8*>(
                    &sm[buf][1][row * 64 + (((kk * 2 + hi) ^ (row & 7)) * 8)]);
            }
#pragma unroll
            for (int mb = 0; mb < 2; ++mb)
#pragma unroll
                for (int nb = 0; nb < 2; ++nb)
                    acc[mb][nb] = mfma32(af[mb], bfr[nb], acc[mb][nb]);
        }
        __builtin_amdgcn_s_setprio(0);
    };

    if (DBUF) {
        stage(0, 0);
        __syncthreads();
        int cur = 0;
        for (int kc = 0; kc < HID; kc += 64) {
            if (kc + 64 < HID) stage(cur ^ 1, kc + 64);
            compute(cur);
            __syncthreads();
            cur ^= 1;
        }
    } else {
        for (int kc = 0; kc < HID; kc += 64) {
            __syncthreads();
            stage(0, kc);
            __syncthreads();
            compute(0);
        }
    }

    if (CMODE == 0) {
        float* C = (float*)Cv;
#pragma unroll
        for (int mb = 0; mb < 2; ++mb)
#pragma unroll
            for (int r = 0; r < 16; ++r) {
                const int m = wm * 64 + mb * 32 + (r & 3) + 8 * (r >> 2) + 4 * hi;
                const int s = tilebase + (m >> 6) * 576 + ((m >> 3) & 7) * 24 + (m & 7);
#pragma unroll
                for (int nb = 0; nb < 2; ++nb) {
                    const int n = n0 + wn * 64 + nb * 32 + l31;
                    C[(size_t)s * HID + n] = acc[mb][nb][r] * av;
                }
            }
    } else {
        u16* C = (u16*)Cv;
#pragma unroll
        for (int mb = 0; mb < 2; ++mb)
#pragma unroll
            for (int rq = 0; rq < 4; ++rq) {
                const int mbase = wm * 64 + mb * 32 + 8 * rq + 4 * hi;
#pragma unroll
                for (int nb = 0; nb < 2; ++nb) {
                    const int n = n0 + wn * 64 + nb * 32 + l31;
                    const int head = n >> 6, dh = n & 63;
                    if (QKV && head >= 32) {
                        // V: write transposed [head][tile][dh][within]
                        u32 w0 = cvt_pk_bf16(acc[mb][nb][rq * 4 + 0], acc[mb][nb][rq * 4 + 1]);
                        u32 w1 = cvt_pk_bf16(acc[mb][nb][rq * 4 + 2], acc[mb][nb][rq * 4 + 3]);
                        *reinterpret_cast<uint2*>(C + (size_t)head * HEADSZ +
                            (size_t)by * 8192 + dh * 128 + mbase) = make_uint2(w0, w1);
                    } else {
#pragma unroll
                        for (int j = 0; j < 4; ++j) {
                            const int m = mbase + j;
                            C[(size_t)head * HEADSZ + (size_t)(by * 128 + m) * 64 + dh] =
                                bf16r(acc[mb][nb][rq * 4 + j] * av);
                        }
                    }
                }
            }
    }
}

// attention: 1152 blocks = (head, q-tile, key-parity); 4 waves = 2qw x 2kw.
// Each wave owns 64 q-rows (qw) x 32 of the 64 staged keys (kw): every
// K/V LDS fragment read feeds TWO MFMAs (2 q-blocks in registers), halving
// LDS-port traffic vs the 32q-per-wave layout (the measured bottleneck).
// kw partials (accO, lsum) merge once at the end through the LDS buffer.
// Register discipline (round-1 lesson): live set ~160 VGPR. waves_per_eu(3,3)
// caps at 168 AND stops the allocator from chasing 6 waves/EU (it hit 84 VGPR
// by rematerializing the Q global loads inside the loop: FETCH 2x, 65% slower).
// The empty-asm pin makes qf non-rematerializable.
// No-max softmax -> partials merge by pure addition in merge_attn.
// XCD-swizzled blockIdx: each XCD owns 2 heads (K/V fit its 4MB L2).
__global__ __attribute__((amdgpu_waves_per_eu(3, 3))) __launch_bounds__(256)
void attn_mfma(const u16* __restrict__ Q, const u16* __restrict__ K,
               const u16* __restrict__ Vt, u16* __restrict__ pO0,
               u16* __restrict__ pO1, float* __restrict__ pl)
{
    __shared__ u16 sm[2][2][4096];   // [buf][K=0 / V=1][64 x 64] = 32 KB
    __shared__ float lsl[2][2][32];  // [qw][qb][q31] kw=1 lsum handoff

    const int tid = threadIdx.x;
    const int wave = tid >> 6;
    const int lane = tid & 63;
    const int l31 = lane & 31;
    const int hi  = lane >> 5;
    const int qw  = wave & 1;
    const int kw  = wave >> 1;

    // XCD-aware bijective swizzle: 1152 = 8 * 144
    const int logical = (blockIdx.x & 7) * 144 + (blockIdx.x >> 3);
    const int p  = logical & 1;
    const int bt = logical >> 1;       // head*36 + tile
    const int tl = bt % NTILES;
    const int hd = bt / NTILES;
    const size_t headbase = (size_t)hd * HEADSZ;

    const u16* Qg = Q + headbase + (size_t)tl * 8192;
    const u16* Kh = K + headbase;
    const u16* Vh = Vt + headbase;

    // 64 q-rows per wave, in registers: [qb][ks]
    bf16x8 qf[2][4];
#pragma unroll
    for (int qb = 0; qb < 2; ++qb) {
        const u16* qrow = Qg + (qw * 64 + qb * 32 + l31) * 64 + hi * 8;
#pragma unroll
        for (int ks = 0; ks < 4; ++ks)
            qf[qb][ks] = *reinterpret_cast<const bf16x8*>(qrow + ks * 16);
    }
    // Pin Q fragments in VGPRs: empty asm ties make them asm-defined values,
    // which the allocator cannot rematerialize from global memory.
#pragma unroll
    for (int qb = 0; qb < 2; ++qb)
#pragma unroll
        for (int ks = 0; ks < 4; ++ks) {
            u32x4 t = __builtin_bit_cast(u32x4, qf[qb][ks]);
            asm volatile("" : "+v"(t));
            qf[qb][ks] = __builtin_bit_cast(bf16x8, t);
        }

    const int base_t = (min(max(tl / 9, 1), 2) - 1) * 9;

    const int srow = lane >> 3;   // 0..7
    const int slot = lane & 7;

    auto stage = [&](int i, int bi) {
        const int kt = base_t + i;
        const u16* Kg = Kh + (size_t)kt * 8192 + p * 4096;
        const u16* Vg = Vh + (size_t)kt * 8192 + p * 64;
        u16* dk = &sm[bi][0][0];
        u16* dv = &sm[bi][1][0];
#pragma unroll
        for (int q = 0; q < 2; ++q) {
            const int seg = wave * 2 + q;
            const int key = seg * 8 + srow;
            gld_lds16(Kg + key * 64 + ((slot ^ (key & 7)) * 8), dk + seg * 512);
            const int dh = seg * 8 + srow;
            gld_lds16(Vg + dh * 128 + ((slot ^ (dh & 7)) * 8), dv + seg * 512);
        }
    };

    f32x16 accO[2][2];  // [dhb][qb]: 64 dh x 64 q partial (this wave's keys)
#pragma unroll
    for (int dhb = 0; dhb < 2; ++dhb)
#pragma unroll
        for (int qb = 0; qb < 2; ++qb)
#pragma unroll
            for (int i = 0; i < 16; ++i) accO[dhb][qb][i] = 0.f;
    float lsum[2] = {0.f, 0.f};

    stage(0, 0);
    __syncthreads();

    const int kr = kw * 32 + l31;

    for (int i = 0; i < 27; ++i) {
        const int cur = i & 1;
        if (i + 1 < 27) stage(i + 1, cur ^ 1);
        const u16* Ksb = &sm[cur][0][0];
        const u16* Vsb = &sm[cur][1][0];

        // K fragments for this wave's 32 keys: read ONCE, used by both qb.
        bf16x8 af[4];
#pragma unroll
        for (int ks = 0; ks < 4; ++ks)
            af[ks] = *reinterpret_cast<const bf16x8*>(
                Ksb + kr * 64 + (((2 * ks + hi) ^ (kr & 7)) * 8));

        bf16x8 pb[2][2];
#pragma unroll
        for (int qb = 0; qb < 2; ++qb) {
            f32x16 s;
#pragma unroll
            for (int i2 = 0; i2 < 16; ++i2) s[i2] = 0.f;
            __builtin_amdgcn_s_setprio(1);
#pragma unroll
            for (int ks = 0; ks < 4; ++ks)
                s = mfma32(af[ks], qf[qb][ks], s);
            __builtin_amdgcn_s_setprio(0);

            // plain exp2 (scores pre-scaled by log2e/8 in Q; bounded, no max)
#pragma unroll
            for (int i2 = 0; i2 < 16; ++i2) s[i2] = __builtin_amdgcn_exp2f(s[i2]);

            float ps = 0.f;
#pragma unroll
            for (int i2 = 0; i2 < 16; ++i2) ps += s[i2];
            lsum[qb] += ps;

            // pack P -> 2 bf16 B-frags (this wave's 32 keys x 32 q)
            u32 a0 = cvt_pk_bf16(s[0], s[1]);
            u32 a1 = cvt_pk_bf16(s[2], s[3]);
            u32 b0 = cvt_pk_bf16(s[4], s[5]);
            u32 b1 = cvt_pk_bf16(s[6], s[7]);
            permlane32_swap(a0, b0);
            permlane32_swap(a1, b1);
            u32x4 w; w.x = a0; w.y = a1; w.z = b0; w.w = b1;
            pb[qb][0] = __builtin_bit_cast(bf16x8, w);
            u32 c0 = cvt_pk_bf16(s[8], s[9]);
            u32 c1 = cvt_pk_bf16(s[10], s[11]);
            u32 d0 = cvt_pk_bf16(s[12], s[13]);
            u32 d1 = cvt_pk_bf16(s[14], s[15]);
            permlane32_swap(c0, d0);
            permlane32_swap(c1, d1);
            u32x4 w2; w2.x = c0; w2.y = c1; w2.z = d0; w2.w = d1;
            pb[qb][1] = __builtin_bit_cast(bf16x8, w2);
        }

        // PV: each V fragment read feeds both qb accumulators.
        __builtin_amdgcn_s_setprio(1);
#pragma unroll
        for (int k2 = 0; k2 < 2; ++k2) {
            const int sg2 = kw * 4 + k2 * 2 + hi;
            bf16x8 v0 = *reinterpret_cast<const bf16x8*>(
                Vsb + l31 * 64 + ((sg2 ^ (l31 & 7)) * 8));
            bf16x8 v1 = *reinterpret_cast<const bf16x8*>(
                Vsb + (32 + l31) * 64 + ((sg2 ^ ((32 + l31) & 7)) * 8));
            accO[0][0] = mfma32(v0, pb[0][k2], accO[0][0]);
            accO[1][0] = mfma32(v1, pb[0][k2], accO[1][0]);
            accO[0][1] = mfma32(v0, pb[1][k2], accO[0][1]);
            accO[1][1] = mfma32(v1, pb[1][k2], accO[1][1]);
        }
        __builtin_amdgcn_s_setprio(0);
        __syncthreads();
    }

    lsum[0] += __shfl_xor(lsum[0], 32);
    lsum[1] += __shfl_xor(lsum[1], 32);

    // cross-kw merge through LDS (loop is done with sm; last sync passed).
    // layout: [qw 2][chunk 16][lane 64][float4] -> 16B/lane stride, no conflicts
    float* fs = reinterpret_cast<float*>(&sm[0][0][0]);
    if (kw == 1) {
#pragma unroll
        for (int dhb = 0; dhb < 2; ++dhb)
#pragma unroll
            for (int qb = 0; qb < 2; ++qb)
#pragma unroll
                for (int r4 = 0; r4 < 4; ++r4) {
                    const int c = (dhb * 2 + qb) * 4 + r4;
                    float4 v = make_float4(accO[dhb][qb][4 * r4 + 0],
                                           accO[dhb][qb][4 * r4 + 1],
                                           accO[dhb][qb][4 * r4 + 2],
                                           accO[dhb][qb][4 * r4 + 3]);
                    *reinterpret_cast<float4*>(&fs[qw * 4096 + c * 256 + lane * 4]) = v;
                }
        if (hi == 0) { lsl[qw][0][l31] = lsum[0]; lsl[qw][1][l31] = lsum[1]; }
    }
    __syncthreads();
    if (kw == 0) {
#pragma unroll
        for (int dhb = 0; dhb < 2; ++dhb)
#pragma unroll
            for (int qb = 0; qb < 2; ++qb)
#pragma unroll
                for (int r4 = 0; r4 < 4; ++r4) {
                    const int c = (dhb * 2 + qb) * 4 + r4;
                    float4 v = *reinterpret_cast<const float4*>(
                        &fs[qw * 4096 + c * 256 + lane * 4]);
                    accO[dhb][qb][4 * r4 + 0] += v.x;
                    accO[dhb][qb][4 * r4 + 1] += v.y;
                    accO[dhb][qb][4 * r4 + 2] += v.z;
                    accO[dhb][qb][4 * r4 + 3] += v.w;
                }
        lsum[0] += lsl[qw][0][l31];
        lsum[1] += lsl[qw][1][l31];

        u16* Ob = (p ? pO1 : pO0) + ((size_t)(bt * 128 + qw * 64)) * 64;
#pragma unroll
        for (int qb = 0; qb < 2; ++qb)
#pragma unroll
            for (int dhb = 0; dhb < 2; ++dhb)
#pragma unroll
                for (int t = 0; t < 4; ++t) {
                    u32 w0 = cvt_pk_bf16(accO[dhb][qb][4 * t + 0], accO[dhb][qb][4 * t + 1]);
                    u32 w1 = cvt_pk_bf16(accO[dhb][qb][4 * t + 2], accO[dhb][qb][4 * t + 3]);
                    *reinterpret_cast<uint2*>(Ob + (qb * 32 + l31) * 64 +
                                              dhb * 32 + t * 8 + 4 * hi) = make_uint2(w0, w1);
                }
        if (hi == 0) {
            pl[p * PLSTRIDE + bt * 128 + qw * 64 + l31]      = lsum[0];
            pl[p * PLSTRIDE + bt * 128 + qw * 64 + 32 + l31] = lsum[1];
        }
    }
}

// merge the two key-parity partials: O = (pO0 + pO1) / (l0 + l1), bf16 tileized
__global__ __launch_bounds__(256)
void merge_attn(const u16* __restrict__ pO0, const u16* __restrict__ pO1,
                const float* __restrict__ pl, u16* __restrict__ O)
{
    const int b = blockIdx.x;          // head*36 + tile
    const int tid = threadIdx.x;
    const int row = tid >> 1;
    const int d0 = (tid & 1) * 32;
    const size_t rbase = ((size_t)b * 128 + row) * 64 + d0;
    const float inv = 1.f / (pl[b * 128 + row] + pl[PLSTRIDE + b * 128 + row]);
#pragma unroll
    for (int g = 0; g < 4; ++g) {
        ushort8v a = *reinterpret_cast<const ushort8v*>(pO0 + rbase + g * 8);
        ushort8v c = *reinterpret_cast<const ushort8v*>(pO1 + rbase + g * 8);
        u32 w[4];
#pragma unroll
        for (int h = 0; h < 4; ++h) {
            float f0 = (bf2f(a[2 * h])     + bf2f(c[2 * h]))     * inv;
            float f1 = (bf2f(a[2 * h + 1]) + bf2f(c[2 * h + 1])) * inv;
            w[h] = cvt_pk_bf16(f0, f1);
        }
        u32x4 st; st.x = w[0]; st.y = w[1]; st.z = w[2]; st.w = w[3];
        *reinterpret_cast<u32x4*>(O + rbase + g * 8) = st;
    }
}

extern "C" void kernel_launch(void* const* d_in, const int* in_sizes, int n_in,
                              void* d_out, int out_size, void* d_ws, size_t ws_size,
                              hipStream_t stream) {
    const float* hs = (const float*)d_in[0];
    const float* qw = (const float*)d_in[1];
    const float* kw = (const float*)d_in[2];
    const float* vw = (const float*)d_in[3];
    const float* ow = (const float*)d_in[4];
    float* out = (float*)d_out;

    const size_t TSZ = (size_t)NHEADS * HEADSZ;
    const size_t WSZ = (size_t)HID * HID;
    u16* hsb = (u16*)d_ws;      // reused as pO0 after the QKV GEMM consumes hs
    u16* wqb = hsb + TSZ;       // wq|wk|wv|wo contiguous
    u16* wkb = wqb + WSZ;
    u16* wvb = wkb + WSZ;
    u16* wob = wvb + WSZ;
    u16* qb  = wob + WSZ;       // q|k|vt contiguous (from fused QKV gemm)
    u16* kb  = qb + TSZ;
    u16* vt  = kb + TSZ;
    u16* pO0 = hsb;
    u16* pO1 = vt + TSZ;
    float* pl = (float*)(pO1 + TSZ);
    u16* aob = (u16*)(pl + 2 * PLSTRIDE);

    CastJob cj;
    cj.src[0] = hs; cj.dst[0] = hsb; cj.n[0] = (int)TSZ;
    cj.src[1] = qw; cj.dst[1] = wqb; cj.n[1] = (int)WSZ;
    cj.src[2] = kw; cj.dst[2] = wkb; cj.n[2] = (int)WSZ;
    cj.src[3] = vw; cj.dst[3] = wvb; cj.n[3] = (int)WSZ;
    cj.src[4] = ow; cj.dst[4] = wob; cj.n[4] = (int)WSZ;
    cast_bf16<<<dim3(2304, 5), 256, 0, stream>>>(cj);

    // fused QKV projection (V written pre-transposed)
    gemm_mfma<0, 1, true, true><<<dim3(24, 36), 256, 0, stream>>>(hsb, wqb, qb, 0.125f * LOG2E);
    attn_mfma<<<NHEADS * NTILES * 2, 256, 0, stream>>>(qb, kb, vt, pO0, pO1, pl);
    merge_attn<<<NHEADS * NTILES, 256, 0, stream>>>(pO0, pO1, pl, aob);
    gemm_mfma<1, 0, false, true><<<dim3(8, 36), 256, 0, stream>>>(aob, wob, out, 1.0f);
}

// Round 3
// 167.319 us; speedup vs baseline: 1.1817x; 1.1565x over previous
//
#include <hip/hip_runtime.h>
#include <math.h>

#define HID 1024
#define NHEADS 16
#define NTILES 36
#define HEADSZ (36*128*64)
#define LOG2E 1.4426950408889634f
#define PLSTRIDE 73728   // 16*36*128

typedef unsigned short u16;
typedef unsigned int u32;
typedef __attribute__((ext_vector_type(8))) u16 ushort8v;
typedef __attribute__((ext_vector_type(8))) __bf16 bf16x8;
typedef __attribute__((ext_vector_type(16))) float f32x16;
typedef __attribute__((ext_vector_type(4))) u32 u32x4;

__device__ __forceinline__ u32 cvt_pk_bf16(float lo, float hi) {
  u32 r;
  asm("v_cvt_pk_bf16_f32 %0, %1, %2" : "=v"(r) : "v"(lo), "v"(hi));
  return r;
}
__device__ __forceinline__ void permlane32_swap(u32 &a, u32 &b) {
  asm volatile("v_permlane32_swap_b32 %0, %1" : "+v"(a), "+v"(b));
}
__device__ __forceinline__ void gld_lds16(const void* g, void* l) {
  __builtin_amdgcn_global_load_lds((const __attribute__((address_space(1))) u32*)g,
                                   (__attribute__((address_space(3))) u32*)l, 16, 0, 0);
}
__device__ __forceinline__ f32x16 mfma32(bf16x8 a, bf16x8 b, f32x16 c) {
  return __builtin_amdgcn_mfma_f32_32x32x16_bf16(a, b, c, 0, 0, 0);
}
__device__ __forceinline__ u16 bf16r(float x) {
  u32 b = __builtin_bit_cast(u32, x);
  b += 0x7fff + ((b >> 16) & 1);
  return (u16)(b >> 16);
}
__device__ __forceinline__ float bf2f(u16 v) {
  return __builtin_bit_cast(float, (u32)v << 16);
}

// ---------------- cast fp32 -> bf16 (5 arrays in one launch) ----------------
struct CastJob { const float* src[5]; u16* dst[5]; int n[5]; };

__global__ __launch_bounds__(256)
void cast_bf16(CastJob j) {
  const int w = blockIdx.y;
  const int n = j.n[w];
  const int i = (blockIdx.x * 256 + threadIdx.x) * 8;
  if (i >= n) return;
  const float4 v0 = *reinterpret_cast<const float4*>(j.src[w] + i);
  const float4 v1 = *reinterpret_cast<const float4*>(j.src[w] + i + 4);
  u32x4 o;
  o.x = cvt_pk_bf16(v0.x, v0.y);
  o.y = cvt_pk_bf16(v0.z, v0.w);
  o.z = cvt_pk_bf16(v1.x, v1.y);
  o.w = cvt_pk_bf16(v1.z, v1.w);
  *reinterpret_cast<u32x4*>(j.dst[w] + i) = o;
}

// ---------------- bf16 MFMA GEMM: C = A @ B^T ----------------
// M iterated in TILEIZED order (blockIdx.y = attention tile, 128 rows).
// AMODE 0: A bf16 row-major [4608][1024].  AMODE 1: A bf16 tileized.
// CMODE 0: C fp32 row-major.               CMODE 1: C bf16 tileized.
// QKV: B/C span q|k|v; heads >=32 (the V section) are written TRANSPOSED
//      ([head][tile][dh][within]) so no separate transpose pass is needed.
// DBUF: double-buffered LDS (64KB) vs single-buffer (32KB).
template<int AMODE, int CMODE, bool QKV, bool DBUF>
__global__ __launch_bounds__(256)
void gemm_mfma(const u16* __restrict__ A, const u16* __restrict__ B,
               void* __restrict__ Cv, float alpha)
{
    __shared__ __align__(16) u16 sm[DBUF ? 2 : 1][2][8192];

    const int tid = threadIdx.x;
    const int wv = tid >> 6, l = tid & 63;
    const int l31 = l & 31, hi = l >> 5;
    const int wm = wv >> 1, wn = wv & 1;
    const int by = blockIdx.y;
    const int n0 = blockIdx.x * 128;
    const float av = (QKV && n0 >= 1024) ? 1.0f : alpha;

    const int tt = by / 9, rem = by % 9, th = rem / 3, tw = rem % 3;
    const int tilebase = tt * 1152 + th * 192 + tw * 8;

    const int lrow = l >> 3;
    const int lslot = l & 7;
    const int sg = (lslot ^ lrow) * 8;
    const u16* aptr[4];
    const u16* bptr[4];
#pragma unroll
    for (int i = 0; i < 4; ++i) {
        const int row = (wv * 4 + i) * 8 + lrow;
        if (AMODE == 0) {
            const int s = tilebase + (row >> 6) * 576 + ((row >> 3) & 7) * 24 + (row & 7);
            aptr[i] = A + (size_t)s * HID + sg;
        } else {
            aptr[i] = A + (size_t)(by * 128 + row) * 64 + sg;
        }
        bptr[i] = B + (size_t)(n0 + row) * HID + sg;
    }

    auto stage = [&](int buf, int kc) {
#pragma unroll
        for (int i = 0; i < 4; ++i) {
            const u16* ga = (AMODE == 0) ? (aptr[i] + kc)
                                         : (aptr[i] + (size_t)(kc >> 6) * HEADSZ);
            gld_lds16(ga, &sm[buf][0][(wv * 4 + i) * 512]);
            gld_lds16(bptr[i] + kc, &sm[buf][1][(wv * 4 + i) * 512]);
        }
    };

    f32x16 acc[2][2];
#pragma unroll
    for (int mb = 0; mb < 2; ++mb)
#pragma unroll
        for (int nb = 0; nb < 2; ++nb)
#pragma unroll
            for (int i = 0; i < 16; ++i) acc[mb][nb][i] = 0.f;

    auto compute = [&](int buf) {
        __builtin_amdgcn_s_setprio(1);
#pragma unroll
        for (int kk = 0; kk < 4; ++kk) {
            bf16x8 af[2], bfr[2];
#pragma unroll
            for (int mb = 0; mb < 2; ++mb) {
                const int row = wm * 64 + mb * 32 + l31;
                af[mb] = *reinterpret_cast<const bf16x8*>(
                    &sm[buf][0][row * 64 + (((kk * 2 + hi) ^ (row & 7)) * 8)]);
            }
#pragma unroll
            for (int nb = 0; nb < 2; ++nb) {
                const int row = wn * 64 + nb * 32 + l31;
                bfr[nb] = *reinterpret_cast<const bf16x8*>(
                    &sm[buf][1][row * 64 + (((kk * 2 + hi) ^ (row & 7)) * 8)]);
            }
#pragma unroll
            for (int mb = 0; mb < 2; ++mb)
#pragma unroll
                for (int nb = 0; nb < 2; ++nb)
                    acc[mb][nb] = mfma32(af[mb], bfr[nb], acc[mb][nb]);
        }
        __builtin_amdgcn_s_setprio(0);
    };

    if (DBUF) {
        stage(0, 0);
        __syncthreads();
        int cur = 0;
        for (int kc = 0; kc < HID; kc += 64) {
            if (kc + 64 < HID) stage(cur ^ 1, kc + 64);
            compute(cur);
            __syncthreads();
            cur ^= 1;
        }
    } else {
        for (int kc = 0; kc < HID; kc += 64) {
            __syncthreads();
            stage(0, kc);
            __syncthreads();
            compute(0);
        }
    }

    if (CMODE == 0) {
        float* C = (float*)Cv;
#pragma unroll
        for (int mb = 0; mb < 2; ++mb)
#pragma unroll
            for (int r = 0; r < 16; ++r) {
                const int m = wm * 64 + mb * 32 + (r & 3) + 8 * (r >> 2) + 4 * hi;
                const int s = tilebase + (m >> 6) * 576 + ((m >> 3) & 7) * 24 + (m & 7);
#pragma unroll
                for (int nb = 0; nb < 2; ++nb) {
                    const int n = n0 + wn * 64 + nb * 32 + l31;
                    C[(size_t)s * HID + n] = acc[mb][nb][r] * av;
                }
            }
    } else {
        u16* C = (u16*)Cv;
#pragma unroll
        for (int mb = 0; mb < 2; ++mb)
#pragma unroll
            for (int rq = 0; rq < 4; ++rq) {
                const int mbase = wm * 64 + mb * 32 + 8 * rq + 4 * hi;
#pragma unroll
                for (int nb = 0; nb < 2; ++nb) {
                    const int n = n0 + wn * 64 + nb * 32 + l31;
                    const int head = n >> 6, dh = n & 63;
                    if (QKV && head >= 32) {
                        // V: write transposed [head][tile][dh][within]
                        u32 w0 = cvt_pk_bf16(acc[mb][nb][rq * 4 + 0], acc[mb][nb][rq * 4 + 1]);
                        u32 w1 = cvt_pk_bf16(acc[mb][nb][rq * 4 + 2], acc[mb][nb][rq * 4 + 3]);
                        *reinterpret_cast<uint2*>(C + (size_t)head * HEADSZ +
                            (size_t)by * 8192 + dh * 128 + mbase) = make_uint2(w0, w1);
                    } else {
#pragma unroll
                        for (int j = 0; j < 4; ++j) {
                            const int m = mbase + j;
                            C[(size_t)head * HEADSZ + (size_t)(by * 128 + m) * 64 + dh] =
                                bf16r(acc[mb][nb][rq * 4 + j] * av);
                        }
                    }
                }
            }
    }
}

// attention: 1152 blocks = (head, q-tile, key-parity); 4 waves = 2qw x 2kw.
// Each wave owns 64 q-rows (qw) x 32 of the 64 staged keys (kw): every
// K/V LDS fragment read feeds TWO MFMAs (2 q-blocks in registers), halving
// LDS-port traffic vs the 32q-per-wave layout (the measured bottleneck).
// kw partials (accO, lsum) merge once at the end through the LDS buffer.
// Register budget (rounds 1-2 lesson): the waves/EU cap is a UNIFIED
// VGPR+AGPR budget. MFMA C/D (accO 64 + s 16 -> AccumOffset 84) takes the
// AGPR side; at 3 waves/EU (168 total) arch VGPRs got 168-84=84 vs ~130
// live -> massive scratch spill (WRITE_SIZE 19->44MB). Need ~84 AGPR +
// ~170 arch ~= 254 regs -> 2 waves/EU (cap 256). 2 blocks/CU x 4 waves =
// 8 waves/CU ~= round-0's 9, so occupancy loss is benign.
// No-max softmax -> partials merge by pure addition in merge_attn.
// XCD-swizzled blockIdx: each XCD owns 2 heads (K/V fit its 4MB L2).
__global__ __launch_bounds__(256, 2)
void attn_mfma(const u16* __restrict__ Q, const u16* __restrict__ K,
               const u16* __restrict__ Vt, u16* __restrict__ pO0,
               u16* __restrict__ pO1, float* __restrict__ pl)
{
    __shared__ u16 sm[2][2][4096];   // [buf][K=0 / V=1][64 x 64] = 32 KB
    __shared__ float lsl[2][2][32];  // [qw][qb][q31] kw=1 lsum handoff

    const int tid = threadIdx.x;
    const int wave = tid >> 6;
    const int lane = tid & 63;
    const int l31 = lane & 31;
    const int hi  = lane >> 5;
    const int qw  = wave & 1;
    const int kw  = wave >> 1;

    // XCD-aware bijective swizzle: 1152 = 8 * 144
    const int logical = (blockIdx.x & 7) * 144 + (blockIdx.x >> 3);
    const int p  = logical & 1;
    const int bt = logical >> 1;       // head*36 + tile
    const int tl = bt % NTILES;
    const int hd = bt / NTILES;
    const size_t headbase = (size_t)hd * HEADSZ;

    const u16* Qg = Q + headbase + (size_t)tl * 8192;
    const u16* Kh = K + headbase;
    const u16* Vh = Vt + headbase;

    // 64 q-rows per wave, in registers: [qb][ks]
    bf16x8 qf[2][4];
#pragma unroll
    for (int qb = 0; qb < 2; ++qb) {
        const u16* qrow = Qg + (qw * 64 + qb * 32 + l31) * 64 + hi * 8;
#pragma unroll
        for (int ks = 0; ks < 4; ++ks)
            qf[qb][ks] = *reinterpret_cast<const bf16x8*>(qrow + ks * 16);
    }
    // Pin Q fragments in VGPRs: empty asm ties make them asm-defined values,
    // which the allocator cannot rematerialize from global memory.
#pragma unroll
    for (int qb = 0; qb < 2; ++qb)
#pragma unroll
        for (int ks = 0; ks < 4; ++ks) {
            u32x4 t = __builtin_bit_cast(u32x4, qf[qb][ks]);
            asm volatile("" : "+v"(t));
            qf[qb][ks] = __builtin_bit_cast(bf16x8, t);
        }

    const int base_t = (min(max(tl / 9, 1), 2) - 1) * 9;

    const int srow = lane >> 3;   // 0..7
    const int slot = lane & 7;

    auto stage = [&](int i, int bi) {
        const int kt = base_t + i;
        const u16* Kg = Kh + (size_t)kt * 8192 + p * 4096;
        const u16* Vg = Vh + (size_t)kt * 8192 + p * 64;
        u16* dk = &sm[bi][0][0];
        u16* dv = &sm[bi][1][0];
#pragma unroll
        for (int q = 0; q < 2; ++q) {
            const int seg = wave * 2 + q;
            const int key = seg * 8 + srow;
            gld_lds16(Kg + key * 64 + ((slot ^ (key & 7)) * 8), dk + seg * 512);
            const int dh = seg * 8 + srow;
            gld_lds16(Vg + dh * 128 + ((slot ^ (dh & 7)) * 8), dv + seg * 512);
        }
    };

    f32x16 accO[2][2];  // [dhb][qb]: 64 dh x 64 q partial (this wave's keys)
#pragma unroll
    for (int dhb = 0; dhb < 2; ++dhb)
#pragma unroll
        for (int qb = 0; qb < 2; ++qb)
#pragma unroll
            for (int i = 0; i < 16; ++i) accO[dhb][qb][i] = 0.f;
    float lsum[2] = {0.f, 0.f};

    stage(0, 0);
    __syncthreads();

    const int kr = kw * 32 + l31;

    for (int i = 0; i < 27; ++i) {
        const int cur = i & 1;
        if (i + 1 < 27) stage(i + 1, cur ^ 1);
        const u16* Ksb = &sm[cur][0][0];
        const u16* Vsb = &sm[cur][1][0];

        // K fragments for this wave's 32 keys: read ONCE, used by both qb.
        bf16x8 af[4];
#pragma unroll
        for (int ks = 0; ks < 4; ++ks)
            af[ks] = *reinterpret_cast<const bf16x8*>(
                Ksb + kr * 64 + (((2 * ks + hi) ^ (kr & 7)) * 8));

        bf16x8 pb[2][2];
#pragma unroll
        for (int qb = 0; qb < 2; ++qb) {
            f32x16 s;
#pragma unroll
            for (int i2 = 0; i2 < 16; ++i2) s[i2] = 0.f;
            __builtin_amdgcn_s_setprio(1);
#pragma unroll
            for (int ks = 0; ks < 4; ++ks)
                s = mfma32(af[ks], qf[qb][ks], s);
            __builtin_amdgcn_s_setprio(0);

            // plain exp2 (scores pre-scaled by log2e/8 in Q; bounded, no max)
#pragma unroll
            for (int i2 = 0; i2 < 16; ++i2) s[i2] = __builtin_amdgcn_exp2f(s[i2]);

            float ps = 0.f;
#pragma unroll
            for (int i2 = 0; i2 < 16; ++i2) ps += s[i2];
            lsum[qb] += ps;

            // pack P -> 2 bf16 B-frags (this wave's 32 keys x 32 q)
            u32 a0 = cvt_pk_bf16(s[0], s[1]);
            u32 a1 = cvt_pk_bf16(s[2], s[3]);
            u32 b0 = cvt_pk_bf16(s[4], s[5]);
            u32 b1 = cvt_pk_bf16(s[6], s[7]);
            permlane32_swap(a0, b0);
            permlane32_swap(a1, b1);
            u32x4 w; w.x = a0; w.y = a1; w.z = b0; w.w = b1;
            pb[qb][0] = __builtin_bit_cast(bf16x8, w);
            u32 c0 = cvt_pk_bf16(s[8], s[9]);
            u32 c1 = cvt_pk_bf16(s[10], s[11]);
            u32 d0 = cvt_pk_bf16(s[12], s[13]);
            u32 d1 = cvt_pk_bf16(s[14], s[15]);
            permlane32_swap(c0, d0);
            permlane32_swap(c1, d1);
            u32x4 w2; w2.x = c0; w2.y = c1; w2.z = d0; w2.w = d1;
            pb[qb][1] = __builtin_bit_cast(bf16x8, w2);
        }

        // PV: each V fragment read feeds both qb accumulators.
        __builtin_amdgcn_s_setprio(1);
#pragma unroll
        for (int k2 = 0; k2 < 2; ++k2) {
            const int sg2 = kw * 4 + k2 * 2 + hi;
            bf16x8 v0 = *reinterpret_cast<const bf16x8*>(
                Vsb + l31 * 64 + ((sg2 ^ (l31 & 7)) * 8));
            bf16x8 v1 = *reinterpret_cast<const bf16x8*>(
                Vsb + (32 + l31) * 64 + ((sg2 ^ ((32 + l31) & 7)) * 8));
            accO[0][0] = mfma32(v0, pb[0][k2], accO[0][0]);
            accO[1][0] = mfma32(v1, pb[0][k2], accO[1][0]);
            accO[0][1] = mfma32(v0, pb[1][k2], accO[0][1]);
            accO[1][1] = mfma32(v1, pb[1][k2], accO[1][1]);
        }
        __builtin_amdgcn_s_setprio(0);
        __syncthreads();
    }

    lsum[0] += __shfl_xor(lsum[0], 32);
    lsum[1] += __shfl_xor(lsum[1], 32);

    // cross-kw merge through LDS (loop is done with sm; last sync passed).
    // layout: [qw 2][chunk 16][lane 64][float4] -> 16B/lane stride, no conflicts
    float* fs = reinterpret_cast<float*>(&sm[0][0][0]);
    if (kw == 1) {
#pragma unroll
        for (int dhb = 0; dhb < 2; ++dhb)
#pragma unroll
            for (int qb = 0; qb < 2; ++qb)
#pragma unroll
                for (int r4 = 0; r4 < 4; ++r4) {
                    const int c = (dhb * 2 + qb) * 4 + r4;
                    float4 v = make_float4(accO[dhb][qb][4 * r4 + 0],
                                           accO[dhb][qb][4 * r4 + 1],
                                           accO[dhb][qb][4 * r4 + 2],
                                           accO[dhb][qb][4 * r4 + 3]);
                    *reinterpret_cast<float4*>(&fs[qw * 4096 + c * 256 + lane * 4]) = v;
                }
        if (hi == 0) { lsl[qw][0][l31] = lsum[0]; lsl[qw][1][l31] = lsum[1]; }
    }
    __syncthreads();
    if (kw == 0) {
#pragma unroll
        for (int dhb = 0; dhb < 2; ++dhb)
#pragma unroll
            for (int qb = 0; qb < 2; ++qb)
#pragma unroll
                for (int r4 = 0; r4 < 4; ++r4) {
                    const int c = (dhb * 2 + qb) * 4 + r4;
                    float4 v = *reinterpret_cast<const float4*>(
                        &fs[qw * 4096 + c * 256 + lane * 4]);
                    accO[dhb][qb][4 * r4 + 0] += v.x;
                    accO[dhb][qb][4 * r4 + 1] += v.y;
                    accO[dhb][qb][4 * r4 + 2] += v.z;
                    accO[dhb][qb][4 * r4 + 3] += v.w;
                }
        lsum[0] += lsl[qw][0][l31];
        lsum[1] += lsl[qw][1][l31];

        u16* Ob = (p ? pO1 : pO0) + ((size_t)(bt * 128 + qw * 64)) * 64;
#pragma unroll
        for (int qb = 0; qb < 2; ++qb)
#pragma unroll
            for (int dhb = 0; dhb < 2; ++dhb)
#pragma unroll
                for (int t = 0; t < 4; ++t) {
                    u32 w0 = cvt_pk_bf16(accO[dhb][qb][4 * t + 0], accO[dhb][qb][4 * t + 1]);
                    u32 w1 = cvt_pk_bf16(accO[dhb][qb][4 * t + 2], accO[dhb][qb][4 * t + 3]);
                    *reinterpret_cast<uint2*>(Ob + (qb * 32 + l31) * 64 +
                                              dhb * 32 + t * 8 + 4 * hi) = make_uint2(w0, w1);
                }
        if (hi == 0) {
            pl[p * PLSTRIDE + bt * 128 + qw * 64 + l31]      = lsum[0];
            pl[p * PLSTRIDE + bt * 128 + qw * 64 + 32 + l31] = lsum[1];
        }
    }
}

// merge the two key-parity partials: O = (pO0 + pO1) / (l0 + l1), bf16 tileized
__global__ __launch_bounds__(256)
void merge_attn(const u16* __restrict__ pO0, const u16* __restrict__ pO1,
                const float* __restrict__ pl, u16* __restrict__ O)
{
    const int b = blockIdx.x;          // head*36 + tile
    const int tid = threadIdx.x;
    const int row = tid >> 1;
    const int d0 = (tid & 1) * 32;
    const size_t rbase = ((size_t)b * 128 + row) * 64 + d0;
    const float inv = 1.f / (pl[b * 128 + row] + pl[PLSTRIDE + b * 128 + row]);
#pragma unroll
    for (int g = 0; g < 4; ++g) {
        ushort8v a = *reinterpret_cast<const ushort8v*>(pO0 + rbase + g * 8);
        ushort8v c = *reinterpret_cast<const ushort8v*>(pO1 + rbase + g * 8);
        u32 w[4];
#pragma unroll
        for (int h = 0; h < 4; ++h) {
            float f0 = (bf2f(a[2 * h])     + bf2f(c[2 * h]))     * inv;
            float f1 = (bf2f(a[2 * h + 1]) + bf2f(c[2 * h + 1])) * inv;
            w[h] = cvt_pk_bf16(f0, f1);
        }
        u32x4 st; st.x = w[0]; st.y = w[1]; st.z = w[2]; st.w = w[3];
        *reinterpret_cast<u32x4*>(O + rbase + g * 8) = st;
    }
}

extern "C" void kernel_launch(void* const* d_in, const int* in_sizes, int n_in,
                              void* d_out, int out_size, void* d_ws, size_t ws_size,
                              hipStream_t stream) {
    const float* hs = (const float*)d_in[0];
    const float* qw = (const float*)d_in[1];
    const float* kw = (const float*)d_in[2];
    const float* vw = (const float*)d_in[3];
    const float* ow = (const float*)d_in[4];
    float* out = (float*)d_out;

    const size_t TSZ = (size_t)NHEADS * HEADSZ;
    const size_t WSZ = (size_t)HID * HID;
    u16* hsb = (u16*)d_ws;      // reused as pO0 after the QKV GEMM consumes hs
    u16* wqb = hsb + TSZ;       // wq|wk|wv|wo contiguous
    u16* wkb = wqb + WSZ;
    u16* wvb = wkb + WSZ;
    u16* wob = wvb + WSZ;
    u16* qb  = wob + WSZ;       // q|k|vt contiguous (from fused QKV gemm)
    u16* kb  = qb + TSZ;
    u16* vt  = kb + TSZ;
    u16* pO0 = hsb;
    u16* pO1 = vt + TSZ;
    float* pl = (float*)(pO1 + TSZ);
    u16* aob = (u16*)(pl + 2 * PLSTRIDE);

    CastJob cj;
    cj.src[0] = hs; cj.dst[0] = hsb; cj.n[0] = (int)TSZ;
    cj.src[1] = qw; cj.dst[1] = wqb; cj.n[1] = (int)WSZ;
    cj.src[2] = kw; cj.dst[2] = wkb; cj.n[2] = (int)WSZ;
    cj.src[3] = vw; cj.dst[3] = wvb; cj.n[3] = (int)WSZ;
    cj.src[4] = ow; cj.dst[4] = wob; cj.n[4] = (int)WSZ;
    cast_bf16<<<dim3(2304, 5), 256, 0, stream>>>(cj);

    // fused QKV projection (V written pre-transposed)
    gemm_mfma<0, 1, true, true><<<dim3(24, 36), 256, 0, stream>>>(hsb, wqb, qb, 0.125f * LOG2E);
    attn_mfma<<<NHEADS * NTILES * 2, 256, 0, stream>>>(qb, kb, vt, pO0, pO1, pl);
    merge_attn<<<NHEADS * NTILES, 256, 0, stream>>>(pO0, pO1, pl, aob);
    gemm_mfma<1, 0, false, true><<<dim3(8, 36), 256, 0, stream>>>(aob, wob, out, 1.0f);
}

// Round 4
// 166.984 us; speedup vs baseline: 1.1840x; 1.0020x over previous
//
#include <hip/hip_runtime.h>
#include <math.h>

#define HID 1024
#define NHEADS 16
#define NTILES 36
#define HEADSZ (36*128*64)
#define LOG2E 1.4426950408889634f
#define PLSTRIDE 73728   // 16*36*128

typedef unsigned short u16;
typedef unsigned int u32;
typedef __attribute__((ext_vector_type(8))) u16 ushort8v;
typedef __attribute__((ext_vector_type(8))) __bf16 bf16x8;
typedef __attribute__((ext_vector_type(16))) float f32x16;
typedef __attribute__((ext_vector_type(4))) u32 u32x4;

__device__ __forceinline__ u32 cvt_pk_bf16(float lo, float hi) {
  u32 r;
  asm("v_cvt_pk_bf16_f32 %0, %1, %2" : "=v"(r) : "v"(lo), "v"(hi));
  return r;
}
__device__ __forceinline__ void permlane32_swap(u32 &a, u32 &b) {
  asm volatile("v_permlane32_swap_b32 %0, %1" : "+v"(a), "+v"(b));
}
__device__ __forceinline__ void gld_lds16(const void* g, void* l) {
  __builtin_amdgcn_global_load_lds((const __attribute__((address_space(1))) u32*)g,
                                   (__attribute__((address_space(3))) u32*)l, 16, 0, 0);
}
__device__ __forceinline__ f32x16 mfma32(bf16x8 a, bf16x8 b, f32x16 c) {
  return __builtin_amdgcn_mfma_f32_32x32x16_bf16(a, b, c, 0, 0, 0);
}
__device__ __forceinline__ u16 bf16r(float x) {
  u32 b = __builtin_bit_cast(u32, x);
  b += 0x7fff + ((b >> 16) & 1);
  return (u16)(b >> 16);
}
__device__ __forceinline__ float bf2f(u16 v) {
  return __builtin_bit_cast(float, (u32)v << 16);
}

// ---------------- cast fp32 -> bf16 (5 arrays in one launch) ----------------
struct CastJob { const float* src[5]; u16* dst[5]; int n[5]; };

__global__ __launch_bounds__(256)
void cast_bf16(CastJob j) {
  const int w = blockIdx.y;
  const int n = j.n[w];
  const int i = (blockIdx.x * 256 + threadIdx.x) * 8;
  if (i >= n) return;
  const float4 v0 = *reinterpret_cast<const float4*>(j.src[w] + i);
  const float4 v1 = *reinterpret_cast<const float4*>(j.src[w] + i + 4);
  u32x4 o;
  o.x = cvt_pk_bf16(v0.x, v0.y);
  o.y = cvt_pk_bf16(v0.z, v0.w);
  o.z = cvt_pk_bf16(v1.x, v1.y);
  o.w = cvt_pk_bf16(v1.z, v1.w);
  *reinterpret_cast<u32x4*>(j.dst[w] + i) = o;
}

// ---------------- bf16 MFMA GEMM: C = A @ B^T ----------------
// M iterated in TILEIZED order (blockIdx.y = attention tile, 128 rows).
// AMODE 0: A bf16 row-major [4608][1024].  AMODE 1: A bf16 tileized.
// AMODE 2: A = merged attn partials: (P0+P1) * 1/(PL0+PL1), bf16 tileized,
//          reg-staged (global->VALU->ds_write) into the SAME linear swizzled
//          LDS slots gld_lds16 would fill -> merge_attn kernel eliminated.
// CMODE 0: C fp32 row-major.               CMODE 1: C bf16 tileized.
// QKV: B/C span q|k|v; heads >=32 (the V section) are written TRANSPOSED
//      ([head][tile][dh][within]) so no separate transpose pass is needed.
// DBUF: double-buffered LDS (64KB) vs single-buffer (32KB).
template<int AMODE, int CMODE, bool QKV, bool DBUF>
__global__ __launch_bounds__(256)
void gemm_mfma(const u16* __restrict__ A, const u16* __restrict__ B,
               void* __restrict__ Cv, float alpha,
               const u16* __restrict__ P0, const u16* __restrict__ P1,
               const float* __restrict__ PL)
{
    __shared__ __align__(16) u16 sm[DBUF ? 2 : 1][2][8192];

    const int tid = threadIdx.x;
    const int wv = tid >> 6, l = tid & 63;
    const int l31 = l & 31, hi = l >> 5;
    const int wm = wv >> 1, wn = wv & 1;
    const int by = blockIdx.y;
    const int n0 = blockIdx.x * 128;
    const float av = (QKV && n0 >= 1024) ? 1.0f : alpha;

    const int tt = by / 9, rem = by % 9, th = rem / 3, tw = rem % 3;
    const int tilebase = tt * 1152 + th * 192 + tw * 8;

    const int lrow = l >> 3;
    const int lslot = l & 7;
    const int sg = (lslot ^ lrow) * 8;
    const u16* aptr[4];
    const u16* bptr[4];
#pragma unroll
    for (int i = 0; i < 4; ++i) {
        const int row = (wv * 4 + i) * 8 + lrow;
        if (AMODE == 0) {
            const int s = tilebase + (row >> 6) * 576 + ((row >> 3) & 7) * 24 + (row & 7);
            aptr[i] = A + (size_t)s * HID + sg;
        } else if (AMODE == 1) {
            aptr[i] = A + (size_t)(by * 128 + row) * 64 + sg;
        } else {
            aptr[i] = nullptr;   // AMODE 2: A comes from P0/P1/PL
        }
        bptr[i] = B + (size_t)(n0 + row) * HID + sg;
    }

    auto stage = [&](int buf, int kc) {
        if constexpr (AMODE == 2) {
            const int head = kc >> 6;
#pragma unroll
            for (int i = 0; i < 4; ++i) {
                const int row = (wv * 4 + i) * 8 + lrow;
                const size_t gb = (size_t)head * HEADSZ +
                                  (size_t)(by * 128 + row) * 64 + sg;
                ushort8v a = *reinterpret_cast<const ushort8v*>(P0 + gb);
                ushort8v c = *reinterpret_cast<const ushort8v*>(P1 + gb);
                const int pli = (head * NTILES + by) * 128 + row;
                const float inv = 1.f / (PL[pli] + PL[PLSTRIDE + pli]);
                u32 w[4];
#pragma unroll
                for (int h = 0; h < 4; ++h) {
                    float f0 = (bf2f(a[2 * h])     + bf2f(c[2 * h]))     * inv;
                    float f1 = (bf2f(a[2 * h + 1]) + bf2f(c[2 * h + 1])) * inv;
                    w[h] = cvt_pk_bf16(f0, f1);
                }
                u32x4 st; st.x = w[0]; st.y = w[1]; st.z = w[2]; st.w = w[3];
                // lane l's 16B at seg base + l*16B: same linear slot gld_lds16 fills
                *reinterpret_cast<u32x4*>(&sm[buf][0][(wv * 4 + i) * 512 + l * 8]) = st;
                gld_lds16(bptr[i] + kc, &sm[buf][1][(wv * 4 + i) * 512]);
            }
        } else {
#pragma unroll
            for (int i = 0; i < 4; ++i) {
                const u16* ga = (AMODE == 0) ? (aptr[i] + kc)
                                             : (aptr[i] + (size_t)(kc >> 6) * HEADSZ);
                gld_lds16(ga, &sm[buf][0][(wv * 4 + i) * 512]);
                gld_lds16(bptr[i] + kc, &sm[buf][1][(wv * 4 + i) * 512]);
            }
        }
    };

    f32x16 acc[2][2];
#pragma unroll
    for (int mb = 0; mb < 2; ++mb)
#pragma unroll
        for (int nb = 0; nb < 2; ++nb)
#pragma unroll
            for (int i = 0; i < 16; ++i) acc[mb][nb][i] = 0.f;

    auto compute = [&](int buf) {
        __builtin_amdgcn_s_setprio(1);
#pragma unroll
        for (int kk = 0; kk < 4; ++kk) {
            bf16x8 af[2], bfr[2];
#pragma unroll
            for (int mb = 0; mb < 2; ++mb) {
                const int row = wm * 64 + mb * 32 + l31;
                af[mb] = *reinterpret_cast<const bf16x8*>(
                    &sm[buf][0][row * 64 + (((kk * 2 + hi) ^ (row & 7)) * 8)]);
            }
#pragma unroll
            for (int nb = 0; nb < 2; ++nb) {
                const int row = wn * 64 + nb * 32 + l31;
                bfr[nb] = *reinterpret_cast<const bf16x8*>(
                    &sm[buf][1][row * 64 + (((kk * 2 + hi) ^ (row & 7)) * 8)]);
            }
#pragma unroll
            for (int mb = 0; mb < 2; ++mb)
#pragma unroll
                for (int nb = 0; nb < 2; ++nb)
                    acc[mb][nb] = mfma32(af[mb], bfr[nb], acc[mb][nb]);
        }
        __builtin_amdgcn_s_setprio(0);
    };

    if (DBUF) {
        stage(0, 0);
        __syncthreads();
        int cur = 0;
        for (int kc = 0; kc < HID; kc += 64) {
            if (kc + 64 < HID) stage(cur ^ 1, kc + 64);
            compute(cur);
            __syncthreads();
            cur ^= 1;
        }
    } else {
        for (int kc = 0; kc < HID; kc += 64) {
            __syncthreads();
            stage(0, kc);
            __syncthreads();
            compute(0);
        }
    }

    if (CMODE == 0) {
        float* C = (float*)Cv;
#pragma unroll
        for (int mb = 0; mb < 2; ++mb)
#pragma unroll
            for (int r = 0; r < 16; ++r) {
                const int m = wm * 64 + mb * 32 + (r & 3) + 8 * (r >> 2) + 4 * hi;
                const int s = tilebase + (m >> 6) * 576 + ((m >> 3) & 7) * 24 + (m & 7);
#pragma unroll
                for (int nb = 0; nb < 2; ++nb) {
                    const int n = n0 + wn * 64 + nb * 32 + l31;
                    C[(size_t)s * HID + n] = acc[mb][nb][r] * av;
                }
            }
    } else {
        u16* C = (u16*)Cv;
#pragma unroll
        for (int mb = 0; mb < 2; ++mb)
#pragma unroll
            for (int rq = 0; rq < 4; ++rq) {
                const int mbase = wm * 64 + mb * 32 + 8 * rq + 4 * hi;
#pragma unroll
                for (int nb = 0; nb < 2; ++nb) {
                    const int n = n0 + wn * 64 + nb * 32 + l31;
                    const int head = n >> 6, dh = n & 63;
                    if (QKV && head >= 32) {
                        // V: write transposed [head][tile][dh][within]
                        u32 w0 = cvt_pk_bf16(acc[mb][nb][rq * 4 + 0], acc[mb][nb][rq * 4 + 1]);
                        u32 w1 = cvt_pk_bf16(acc[mb][nb][rq * 4 + 2], acc[mb][nb][rq * 4 + 3]);
                        *reinterpret_cast<uint2*>(C + (size_t)head * HEADSZ +
                            (size_t)by * 8192 + dh * 128 + mbase) = make_uint2(w0, w1);
                    } else {
#pragma unroll
                        for (int j = 0; j < 4; ++j) {
                            const int m = mbase + j;
                            C[(size_t)head * HEADSZ + (size_t)(by * 128 + m) * 64 + dh] =
                                bf16r(acc[mb][nb][rq * 4 + j] * av);
                        }
                    }
                }
            }
    }
}

// attention: 1152 blocks = (head, q-tile, key-parity); 4 waves x 32 q-rows.
// parity p handles the p-th 64-key half of each of the 27 neighbor tiles.
// ROUND-0 STRUCTURE (restored): rounds 1-3 falsified the 64q-per-wave LDS-
// halving redesign — the kernel is latency-bound on the QK->exp2->pack->PV
// chain; occupancy (29% here) hides it, and the redesign's register cost
// halved occupancy for a net loss (84 -> 101..138 us).
// No-max softmax -> partials merge by pure addition (fused into final GEMM).
// XCD-swizzled blockIdx: each XCD owns 2 heads (K/V fit its 4MB L2).
__global__ __launch_bounds__(256, 5)
void attn_mfma(const u16* __restrict__ Q, const u16* __restrict__ K,
               const u16* __restrict__ Vt, u16* __restrict__ pO0,
               u16* __restrict__ pO1, float* __restrict__ pl)
{
    __shared__ u16 sm[2][2][4096];   // [buf][K=0 / V=1][64 x 64] = 32 KB

    const int tid = threadIdx.x;
    const int wave = tid >> 6;
    const int lane = tid & 63;
    const int l31 = lane & 31;
    const int hi  = lane >> 5;

    // XCD-aware bijective swizzle: 1152 = 8 * 144
    const int logical = (blockIdx.x & 7) * 144 + (blockIdx.x >> 3);
    const int p  = logical & 1;
    const int bt = logical >> 1;       // head*36 + tile
    const int tl = bt % NTILES;
    const int hd = bt / NTILES;
    const size_t headbase = (size_t)hd * HEADSZ;

    const u16* Qg = Q + headbase + (size_t)tl * 8192;
    const u16* Kh = K + headbase;
    const u16* Vh = Vt + headbase;

    bf16x8 qf[4];
    {
        const u16* qrow = Qg + (wave * 32 + l31) * 64 + hi * 8;
#pragma unroll
        for (int ks = 0; ks < 4; ++ks)
            qf[ks] = *reinterpret_cast<const bf16x8*>(qrow + ks * 16);
    }

    const int base_t = (min(max(tl / 9, 1), 2) - 1) * 9;

    const int srow = lane >> 3;   // 0..7
    const int slot = lane & 7;

    auto stage = [&](int i, int bi) {
        const int kt = base_t + i;
        const u16* Kg = Kh + (size_t)kt * 8192 + p * 4096;
        const u16* Vg = Vh + (size_t)kt * 8192 + p * 64;
        u16* dk = &sm[bi][0][0];
        u16* dv = &sm[bi][1][0];
#pragma unroll
        for (int q = 0; q < 2; ++q) {
            const int seg = wave * 2 + q;
            const int key = seg * 8 + srow;
            gld_lds16(Kg + key * 64 + ((slot ^ (key & 7)) * 8), dk + seg * 512);
            const int dh = seg * 8 + srow;
            gld_lds16(Vg + dh * 128 + ((slot ^ (dh & 7)) * 8), dv + seg * 512);
        }
    };

    f32x16 accO0, accO1;
#pragma unroll
    for (int i = 0; i < 16; ++i) { accO0[i] = 0.f; accO1[i] = 0.f; }
    float lsum = 0.f;

    stage(0, 0);
    __syncthreads();

    for (int i = 0; i < 27; ++i) {
        const int cur = i & 1;
        if (i + 1 < 27) stage(i + 1, cur ^ 1);
        const u16* Ksb = &sm[cur][0][0];
        const u16* Vsb = &sm[cur][1][0];

#pragma unroll
        for (int c = 0; c < 2; ++c) {
            f32x16 s;
#pragma unroll
            for (int i2 = 0; i2 < 16; ++i2) s[i2] = 0.f;
            const int kr = c * 32 + l31;
            __builtin_amdgcn_s_setprio(1);
#pragma unroll
            for (int ks = 0; ks < 4; ++ks) {
                bf16x8 a = *reinterpret_cast<const bf16x8*>(
                    Ksb + kr * 64 + (((2 * ks + hi) ^ (kr & 7)) * 8));
                s = mfma32(a, qf[ks], s);
            }
            __builtin_amdgcn_s_setprio(0);

            // plain exp2 (scores pre-scaled by log2e/8 in Q; bounded, no max)
#pragma unroll
            for (int i2 = 0; i2 < 16; ++i2) s[i2] = __builtin_amdgcn_exp2f(s[i2]);

            float ps = 0.f;
#pragma unroll
            for (int i2 = 0; i2 < 16; ++i2) ps += s[i2];
            lsum += ps;

            // pack P -> 2 bf16 B-frags (32 keys)
            bf16x8 pb[2];
            {
                u32 a0 = cvt_pk_bf16(s[0], s[1]);
                u32 a1 = cvt_pk_bf16(s[2], s[3]);
                u32 b0 = cvt_pk_bf16(s[4], s[5]);
                u32 b1 = cvt_pk_bf16(s[6], s[7]);
                permlane32_swap(a0, b0);
                permlane32_swap(a1, b1);
                u32x4 w; w.x = a0; w.y = a1; w.z = b0; w.w = b1;
                pb[0] = __builtin_bit_cast(bf16x8, w);
                u32 c0 = cvt_pk_bf16(s[8], s[9]);
                u32 c1 = cvt_pk_bf16(s[10], s[11]);
                u32 d0 = cvt_pk_bf16(s[12], s[13]);
                u32 d1 = cvt_pk_bf16(s[14], s[15]);
                permlane32_swap(c0, d0);
                permlane32_swap(c1, d1);
                u32x4 w2; w2.x = c0; w2.y = c1; w2.z = d0; w2.w = d1;
                pb[1] = __builtin_bit_cast(bf16x8, w2);
            }

            __builtin_amdgcn_s_setprio(1);
#pragma unroll
            for (int k2 = 0; k2 < 2; ++k2) {
                const int sg2 = c * 4 + k2 * 2 + hi;
                bf16x8 v0 = *reinterpret_cast<const bf16x8*>(
                    Vsb + l31 * 64 + ((sg2 ^ (l31 & 7)) * 8));
                accO0 = mfma32(v0, pb[k2], accO0);
                bf16x8 v1 = *reinterpret_cast<const bf16x8*>(
                    Vsb + (32 + l31) * 64 + ((sg2 ^ (l31 & 7)) * 8));
                accO1 = mfma32(v1, pb[k2], accO1);
            }
            __builtin_amdgcn_s_setprio(0);
        }
        __syncthreads();
    }

    lsum += __shfl_xor(lsum, 32);

    u16* Ob = (p ? pO1 : pO0) + ((size_t)bt * 128 + wave * 32 + l31) * 64;
#pragma unroll
    for (int t = 0; t < 4; ++t) {
        u32 p0 = cvt_pk_bf16(accO0[4 * t], accO0[4 * t + 1]);
        u32 p1 = cvt_pk_bf16(accO0[4 * t + 2], accO0[4 * t + 3]);
        *reinterpret_cast<uint2*>(Ob + t * 8 + 4 * hi) = make_uint2(p0, p1);
        u32 q0 = cvt_pk_bf16(accO1[4 * t], accO1[4 * t + 1]);
        u32 q1 = cvt_pk_bf16(accO1[4 * t + 2], accO1[4 * t + 3]);
        *reinterpret_cast<uint2*>(Ob + 32 + t * 8 + 4 * hi) = make_uint2(q0, q1);
    }
    if (hi == 0) pl[p * PLSTRIDE + bt * 128 + wave * 32 + l31] = lsum;
}

extern "C" void kernel_launch(void* const* d_in, const int* in_sizes, int n_in,
                              void* d_out, int out_size, void* d_ws, size_t ws_size,
                              hipStream_t stream) {
    const float* hs = (const float*)d_in[0];
    const float* qw = (const float*)d_in[1];
    const float* kw = (const float*)d_in[2];
    const float* vw = (const float*)d_in[3];
    const float* ow = (const float*)d_in[4];
    float* out = (float*)d_out;

    const size_t TSZ = (size_t)NHEADS * HEADSZ;
    const size_t WSZ = (size_t)HID * HID;
    u16* hsb = (u16*)d_ws;      // reused as pO0 after the QKV GEMM consumes hs
    u16* wqb = hsb + TSZ;       // wq|wk|wv|wo contiguous
    u16* wkb = wqb + WSZ;
    u16* wvb = wkb + WSZ;
    u16* wob = wvb + WSZ;
    u16* qb  = wob + WSZ;       // q|k|vt contiguous (from fused QKV gemm)
    u16* kb  = qb + TSZ;
    u16* vt  = kb + TSZ;
    u16* pO0 = hsb;
    u16* pO1 = vt + TSZ;
    float* pl = (float*)(pO1 + TSZ);

    CastJob cj;
    cj.src[0] = hs; cj.dst[0] = hsb; cj.n[0] = (int)TSZ;
    cj.src[1] = qw; cj.dst[1] = wqb; cj.n[1] = (int)WSZ;
    cj.src[2] = kw; cj.dst[2] = wkb; cj.n[2] = (int)WSZ;
    cj.src[3] = vw; cj.dst[3] = wvb; cj.n[3] = (int)WSZ;
    cj.src[4] = ow; cj.dst[4] = wob; cj.n[4] = (int)WSZ;
    cast_bf16<<<dim3(2304, 5), 256, 0, stream>>>(cj);

    // fused QKV projection (V written pre-transposed)
    gemm_mfma<0, 1, true, true><<<dim3(24, 36), 256, 0, stream>>>(
        hsb, wqb, qb, 0.125f * LOG2E, nullptr, nullptr, nullptr);
    attn_mfma<<<NHEADS * NTILES * 2, 256, 0, stream>>>(qb, kb, vt, pO0, pO1, pl);
    // output projection with fused parity-merge + 1/l normalization (AMODE 2)
    gemm_mfma<2, 0, false, true><<<dim3(8, 36), 256, 0, stream>>>(
        pO0, wob, out, 1.0f, pO0, pO1, pl);
}

// Round 5
// 163.840 us; speedup vs baseline: 1.2067x; 1.0192x over previous
//
#include <hip/hip_runtime.h>
#include <math.h>

#define HID 1024
#define NHEADS 16
#define NTILES 36
#define HEADSZ (36*128*64)
#define LOG2E 1.4426950408889634f
#define PLSTRIDE 73728   // 16*36*128

typedef unsigned short u16;
typedef unsigned int u32;
typedef __attribute__((ext_vector_type(8))) u16 ushort8v;
typedef __attribute__((ext_vector_type(8))) __bf16 bf16x8;
typedef __attribute__((ext_vector_type(16))) float f32x16;
typedef __attribute__((ext_vector_type(4))) u32 u32x4;

__device__ __forceinline__ u32 cvt_pk_bf16(float lo, float hi) {
  u32 r;
  asm("v_cvt_pk_bf16_f32 %0, %1, %2" : "=v"(r) : "v"(lo), "v"(hi));
  return r;
}
__device__ __forceinline__ void permlane32_swap(u32 &a, u32 &b) {
  asm volatile("v_permlane32_swap_b32 %0, %1" : "+v"(a), "+v"(b));
}
__device__ __forceinline__ void gld_lds16(const void* g, void* l) {
  __builtin_amdgcn_global_load_lds((const __attribute__((address_space(1))) u32*)g,
                                   (__attribute__((address_space(3))) u32*)l, 16, 0, 0);
}
__device__ __forceinline__ f32x16 mfma32(bf16x8 a, bf16x8 b, f32x16 c) {
  return __builtin_amdgcn_mfma_f32_32x32x16_bf16(a, b, c, 0, 0, 0);
}
__device__ __forceinline__ u16 bf16r(float x) {
  u32 b = __builtin_bit_cast(u32, x);
  b += 0x7fff + ((b >> 16) & 1);
  return (u16)(b >> 16);
}
__device__ __forceinline__ float bf2f(u16 v) {
  return __builtin_bit_cast(float, (u32)v << 16);
}

// ---------------- cast fp32 -> bf16 (5 arrays in one launch) ----------------
struct CastJob { const float* src[5]; u16* dst[5]; int n[5]; };

__global__ __launch_bounds__(256)
void cast_bf16(CastJob j) {
  const int w = blockIdx.y;
  const int n = j.n[w];
  const int i = (blockIdx.x * 256 + threadIdx.x) * 8;
  if (i >= n) return;
  const float4 v0 = *reinterpret_cast<const float4*>(j.src[w] + i);
  const float4 v1 = *reinterpret_cast<const float4*>(j.src[w] + i + 4);
  u32x4 o;
  o.x = cvt_pk_bf16(v0.x, v0.y);
  o.y = cvt_pk_bf16(v0.z, v0.w);
  o.z = cvt_pk_bf16(v1.x, v1.y);
  o.w = cvt_pk_bf16(v1.z, v1.w);
  *reinterpret_cast<u32x4*>(j.dst[w] + i) = o;
}

// ---------------- bf16 MFMA GEMM: C = A @ B^T (round-0 structure) ----------
// M iterated in TILEIZED order (blockIdx.y = attention tile, 128 rows).
// AMODE 0: A bf16 row-major [4608][1024].  AMODE 1: A bf16 tileized.
// CMODE 0: C fp32 row-major.               CMODE 1: C bf16 tileized.
// QKV: B/C span q|k|v; heads >=32 (the V section) are written TRANSPOSED
//      ([head][tile][dh][within]) so no separate transpose pass is needed.
template<int AMODE, int CMODE, bool QKV, bool DBUF>
__global__ __launch_bounds__(256)
void gemm_mfma(const u16* __restrict__ A, const u16* __restrict__ B,
               void* __restrict__ Cv, float alpha)
{
    __shared__ __align__(16) u16 sm[DBUF ? 2 : 1][2][8192];

    const int tid = threadIdx.x;
    const int wv = tid >> 6, l = tid & 63;
    const int l31 = l & 31, hi = l >> 5;
    const int wm = wv >> 1, wn = wv & 1;
    const int by = blockIdx.y;
    const int n0 = blockIdx.x * 128;
    const float av = (QKV && n0 >= 1024) ? 1.0f : alpha;

    const int tt = by / 9, rem = by % 9, th = rem / 3, tw = rem % 3;
    const int tilebase = tt * 1152 + th * 192 + tw * 8;

    const int lrow = l >> 3;
    const int lslot = l & 7;
    const int sg = (lslot ^ lrow) * 8;
    const u16* aptr[4];
    const u16* bptr[4];
#pragma unroll
    for (int i = 0; i < 4; ++i) {
        const int row = (wv * 4 + i) * 8 + lrow;
        if (AMODE == 0) {
            const int s = tilebase + (row >> 6) * 576 + ((row >> 3) & 7) * 24 + (row & 7);
            aptr[i] = A + (size_t)s * HID + sg;
        } else {
            aptr[i] = A + (size_t)(by * 128 + row) * 64 + sg;
        }
        bptr[i] = B + (size_t)(n0 + row) * HID + sg;
    }

    auto stage = [&](int buf, int kc) {
#pragma unroll
        for (int i = 0; i < 4; ++i) {
            const u16* ga = (AMODE == 0) ? (aptr[i] + kc)
                                         : (aptr[i] + (size_t)(kc >> 6) * HEADSZ);
            gld_lds16(ga, &sm[buf][0][(wv * 4 + i) * 512]);
            gld_lds16(bptr[i] + kc, &sm[buf][1][(wv * 4 + i) * 512]);
        }
    };

    f32x16 acc[2][2];
#pragma unroll
    for (int mb = 0; mb < 2; ++mb)
#pragma unroll
        for (int nb = 0; nb < 2; ++nb)
#pragma unroll
            for (int i = 0; i < 16; ++i) acc[mb][nb][i] = 0.f;

    auto compute = [&](int buf) {
        __builtin_amdgcn_s_setprio(1);
#pragma unroll
        for (int kk = 0; kk < 4; ++kk) {
            bf16x8 af[2], bfr[2];
#pragma unroll
            for (int mb = 0; mb < 2; ++mb) {
                const int row = wm * 64 + mb * 32 + l31;
                af[mb] = *reinterpret_cast<const bf16x8*>(
                    &sm[buf][0][row * 64 + (((kk * 2 + hi) ^ (row & 7)) * 8)]);
            }
#pragma unroll
            for (int nb = 0; nb < 2; ++nb) {
                const int row = wn * 64 + nb * 32 + l31;
                bfr[nb] = *reinterpret_cast<const bf16x8*>(
                    &sm[buf][1][row * 64 + (((kk * 2 + hi) ^ (row & 7)) * 8)]);
            }
#pragma unroll
            for (int mb = 0; mb < 2; ++mb)
#pragma unroll
                for (int nb = 0; nb < 2; ++nb)
                    acc[mb][nb] = mfma32(af[mb], bfr[nb], acc[mb][nb]);
        }
        __builtin_amdgcn_s_setprio(0);
    };

    if (DBUF) {
        stage(0, 0);
        __syncthreads();
        int cur = 0;
        for (int kc = 0; kc < HID; kc += 64) {
            if (kc + 64 < HID) stage(cur ^ 1, kc + 64);
            compute(cur);
            __syncthreads();
            cur ^= 1;
        }
    } else {
        for (int kc = 0; kc < HID; kc += 64) {
            __syncthreads();
            stage(0, kc);
            __syncthreads();
            compute(0);
        }
    }

    if (CMODE == 0) {
        float* C = (float*)Cv;
#pragma unroll
        for (int mb = 0; mb < 2; ++mb)
#pragma unroll
            for (int r = 0; r < 16; ++r) {
                const int m = wm * 64 + mb * 32 + (r & 3) + 8 * (r >> 2) + 4 * hi;
                const int s = tilebase + (m >> 6) * 576 + ((m >> 3) & 7) * 24 + (m & 7);
#pragma unroll
                for (int nb = 0; nb < 2; ++nb) {
                    const int n = n0 + wn * 64 + nb * 32 + l31;
                    C[(size_t)s * HID + n] = acc[mb][nb][r] * av;
                }
            }
    } else {
        u16* C = (u16*)Cv;
#pragma unroll
        for (int mb = 0; mb < 2; ++mb)
#pragma unroll
            for (int rq = 0; rq < 4; ++rq) {
                const int mbase = wm * 64 + mb * 32 + 8 * rq + 4 * hi;
#pragma unroll
                for (int nb = 0; nb < 2; ++nb) {
                    const int n = n0 + wn * 64 + nb * 32 + l31;
                    const int head = n >> 6, dh = n & 63;
                    if (QKV && head >= 32) {
                        // V: write transposed [head][tile][dh][within]
                        u32 w0 = cvt_pk_bf16(acc[mb][nb][rq * 4 + 0], acc[mb][nb][rq * 4 + 1]);
                        u32 w1 = cvt_pk_bf16(acc[mb][nb][rq * 4 + 2], acc[mb][nb][rq * 4 + 3]);
                        *reinterpret_cast<uint2*>(C + (size_t)head * HEADSZ +
                            (size_t)by * 8192 + dh * 128 + mbase) = make_uint2(w0, w1);
                    } else {
#pragma unroll
                        for (int j = 0; j < 4; ++j) {
                            const int m = mbase + j;
                            C[(size_t)head * HEADSZ + (size_t)(by * 128 + m) * 64 + dh] =
                                bf16r(acc[mb][nb][rq * 4 + j] * av);
                        }
                    }
                }
            }
    }
}

// ---------------- output projection w/ fused parity-merge + 1/l norm --------
// C[s][n] = sum_k ((P0+P1)[m,k] * inv_l[m,head(k)]) * W[n,k], fp32 tileized-row.
// 64m x 128n tiles, grid (8,72) = 576 blocks (2.25/CU, imbalance 1.33x vs
// round-4's 288@2/CU = 1.78x). Round-4 lesson: reg-staged merge must be T14-
// split — A loads + PL issued BEFORE compute (latency hides under MFMA), the
// VALU merge + ds_write AFTER compute; rcp not div (full div = ~12 ops).
__global__ __launch_bounds__(256)
void gemm_out(const u16* __restrict__ P0, const u16* __restrict__ P1,
              const float* __restrict__ PL, const u16* __restrict__ B,
              float* __restrict__ C)
{
    __shared__ __align__(16) u16 smA[2][4096];   // [buf][64 x 64]  8 KB/buf
    __shared__ __align__(16) u16 smB[2][8192];   // [buf][128 x 64] 16 KB/buf

    const int tid = threadIdx.x;
    const int wv = tid >> 6, l = tid & 63;
    const int l31 = l & 31, hi = l >> 5;
    const int wm = wv >> 1, wn = wv & 1;
    const int by = blockIdx.y;           // 0..71: tile = by>>1, half = by&1
    const int n0 = blockIdx.x * 128;

    const int tile = by >> 1;
    const int tt = tile / 9, rem = tile % 9, th = rem / 3, tw = rem % 3;
    const int tilebase = tt * 1152 + th * 192 + tw * 8;

    const int lrow = l >> 3;
    const int lslot = l & 7;
    const int sg = (lslot ^ lrow) * 8;

    const u16* bptr[4];
#pragma unroll
    for (int i = 0; i < 4; ++i) {
        const int row = (wv * 4 + i) * 8 + lrow;
        bptr[i] = B + (size_t)(n0 + row) * HID + sg;
    }
    int arow[2];
#pragma unroll
    for (int i = 0; i < 2; ++i) arow[i] = (wv * 2 + i) * 8 + lrow;

    auto stageB = [&](int buf, int kc) {
#pragma unroll
        for (int i = 0; i < 4; ++i)
            gld_lds16(bptr[i] + kc, &smB[buf][(wv * 4 + i) * 512]);
    };

    ushort8v a0[2], a1[2];
    float ls[2];
    auto loadA = [&](int kc) {           // ISSUE EARLY (before compute)
        const int head = kc >> 6;
#pragma unroll
        for (int i = 0; i < 2; ++i) {
            const size_t gb = (size_t)head * HEADSZ +
                              (size_t)(by * 64 + arow[i]) * 64 + sg;
            a0[i] = *reinterpret_cast<const ushort8v*>(P0 + gb);
            a1[i] = *reinterpret_cast<const ushort8v*>(P1 + gb);
            const int pli = head * 4608 + by * 64 + arow[i];
            ls[i] = PL[pli] + PL[PLSTRIDE + pli];
        }
    };
    auto mergeA = [&](int buf) {         // WRITE LATE (after compute)
#pragma unroll
        for (int i = 0; i < 2; ++i) {
            const float r = __builtin_amdgcn_rcpf(ls[i]);
            u32 w[4];
#pragma unroll
            for (int h = 0; h < 4; ++h) {
                float f0 = (bf2f(a0[i][2 * h])     + bf2f(a1[i][2 * h]))     * r;
                float f1 = (bf2f(a0[i][2 * h + 1]) + bf2f(a1[i][2 * h + 1])) * r;
                w[h] = cvt_pk_bf16(f0, f1);
            }
            u32x4 st; st.x = w[0]; st.y = w[1]; st.z = w[2]; st.w = w[3];
            *reinterpret_cast<u32x4*>(&smA[buf][(wv * 2 + i) * 512 + l * 8]) = st;
        }
    };

    f32x16 acc[2];
#pragma unroll
    for (int nb = 0; nb < 2; ++nb)
#pragma unroll
        for (int i = 0; i < 16; ++i) acc[nb][i] = 0.f;

    auto compute = [&](int buf) {
        __builtin_amdgcn_s_setprio(1);
#pragma unroll
        for (int kk = 0; kk < 4; ++kk) {
            const int ar = wm * 32 + l31;
            bf16x8 af = *reinterpret_cast<const bf16x8*>(
                &smA[buf][ar * 64 + (((kk * 2 + hi) ^ (ar & 7)) * 8)]);
#pragma unroll
            for (int nb = 0; nb < 2; ++nb) {
                const int brow = wn * 64 + nb * 32 + l31;
                bf16x8 bf_ = *reinterpret_cast<const bf16x8*>(
                    &smB[buf][brow * 64 + (((kk * 2 + hi) ^ (brow & 7)) * 8)]);
                acc[nb] = mfma32(af, bf_, acc[nb]);
            }
        }
        __builtin_amdgcn_s_setprio(0);
    };

    loadA(0);
    stageB(0, 0);
    mergeA(0);
    __syncthreads();
    int cur = 0;
    for (int kc = 0; kc < HID; kc += 64) {
        const bool more = (kc + 64 < HID);
        if (more) { loadA(kc + 64); stageB(cur ^ 1, kc + 64); }
        compute(cur);
        if (more) mergeA(cur ^ 1);
        __syncthreads();
        cur ^= 1;
    }

#pragma unroll
    for (int r = 0; r < 16; ++r) {
        const int m = wm * 32 + (r & 3) + 8 * (r >> 2) + 4 * hi;
        const int r128 = (by & 1) * 64 + m;
        const int s = tilebase + (r128 >> 6) * 576 + ((r128 >> 3) & 7) * 24 + (r128 & 7);
#pragma unroll
        for (int nb = 0; nb < 2; ++nb) {
            const int n = n0 + wn * 64 + nb * 32 + l31;
            C[(size_t)s * HID + n] = acc[nb][r];
        }
    }
}

// attention: 1152 blocks = (head, q-tile, key-parity); 4 waves x 32 q-rows.
// parity p handles the p-th 64-key half of each of the 27 neighbor tiles.
// ROUND-0 STRUCTURE: rounds 1-3 falsified the 64q-per-wave LDS-halving
// redesign — latency-bound on the QK->exp2->pack->PV chain; occupancy hides
// it; the redesign's register cost halved occupancy for a net loss.
// No-max softmax -> partials merge by pure addition (fused into gemm_out).
// XCD-swizzled blockIdx: each XCD owns 2 heads (K/V fit its 4MB L2).
__global__ __launch_bounds__(256, 5)
void attn_mfma(const u16* __restrict__ Q, const u16* __restrict__ K,
               const u16* __restrict__ Vt, u16* __restrict__ pO0,
               u16* __restrict__ pO1, float* __restrict__ pl)
{
    __shared__ u16 sm[2][2][4096];   // [buf][K=0 / V=1][64 x 64] = 32 KB

    const int tid = threadIdx.x;
    const int wave = tid >> 6;
    const int lane = tid & 63;
    const int l31 = lane & 31;
    const int hi  = lane >> 5;

    // XCD-aware bijective swizzle: 1152 = 8 * 144
    const int logical = (blockIdx.x & 7) * 144 + (blockIdx.x >> 3);
    const int p  = logical & 1;
    const int bt = logical >> 1;       // head*36 + tile
    const int tl = bt % NTILES;
    const int hd = bt / NTILES;
    const size_t headbase = (size_t)hd * HEADSZ;

    const u16* Qg = Q + headbase + (size_t)tl * 8192;
    const u16* Kh = K + headbase;
    const u16* Vh = Vt + headbase;

    bf16x8 qf[4];
    {
        const u16* qrow = Qg + (wave * 32 + l31) * 64 + hi * 8;
#pragma unroll
        for (int ks = 0; ks < 4; ++ks)
            qf[ks] = *reinterpret_cast<const bf16x8*>(qrow + ks * 16);
    }

    const int base_t = (min(max(tl / 9, 1), 2) - 1) * 9;

    const int srow = lane >> 3;   // 0..7
    const int slot = lane & 7;

    auto stage = [&](int i, int bi) {
        const int kt = base_t + i;
        const u16* Kg = Kh + (size_t)kt * 8192 + p * 4096;
        const u16* Vg = Vh + (size_t)kt * 8192 + p * 64;
        u16* dk = &sm[bi][0][0];
        u16* dv = &sm[bi][1][0];
#pragma unroll
        for (int q = 0; q < 2; ++q) {
            const int seg = wave * 2 + q;
            const int key = seg * 8 + srow;
            gld_lds16(Kg + key * 64 + ((slot ^ (key & 7)) * 8), dk + seg * 512);
            const int dh = seg * 8 + srow;
            gld_lds16(Vg + dh * 128 + ((slot ^ (dh & 7)) * 8), dv + seg * 512);
        }
    };

    f32x16 accO0, accO1;
#pragma unroll
    for (int i = 0; i < 16; ++i) { accO0[i] = 0.f; accO1[i] = 0.f; }
    float lsum = 0.f;

    stage(0, 0);
    __syncthreads();

    for (int i = 0; i < 27; ++i) {
        const int cur = i & 1;
        if (i + 1 < 27) stage(i + 1, cur ^ 1);
        const u16* Ksb = &sm[cur][0][0];
        const u16* Vsb = &sm[cur][1][0];

#pragma unroll
        for (int c = 0; c < 2; ++c) {
            f32x16 s;
#pragma unroll
            for (int i2 = 0; i2 < 16; ++i2) s[i2] = 0.f;
            const int kr = c * 32 + l31;
            __builtin_amdgcn_s_setprio(1);
#pragma unroll
            for (int ks = 0; ks < 4; ++ks) {
                bf16x8 a = *reinterpret_cast<const bf16x8*>(
                    Ksb + kr * 64 + (((2 * ks + hi) ^ (kr & 7)) * 8));
                s = mfma32(a, qf[ks], s);
            }
            __builtin_amdgcn_s_setprio(0);

            // plain exp2 (scores pre-scaled by log2e/8 in Q; bounded, no max)
#pragma unroll
            for (int i2 = 0; i2 < 16; ++i2) s[i2] = __builtin_amdgcn_exp2f(s[i2]);

            float ps = 0.f;
#pragma unroll
            for (int i2 = 0; i2 < 16; ++i2) ps += s[i2];
            lsum += ps;

            // pack P -> 2 bf16 B-frags (32 keys)
            bf16x8 pb[2];
            {
                u32 a0 = cvt_pk_bf16(s[0], s[1]);
                u32 a1 = cvt_pk_bf16(s[2], s[3]);
                u32 b0 = cvt_pk_bf16(s[4], s[5]);
                u32 b1 = cvt_pk_bf16(s[6], s[7]);
                permlane32_swap(a0, b0);
                permlane32_swap(a1, b1);
                u32x4 w; w.x = a0; w.y = a1; w.z = b0; w.w = b1;
                pb[0] = __builtin_bit_cast(bf16x8, w);
                u32 c0 = cvt_pk_bf16(s[8], s[9]);
                u32 c1 = cvt_pk_bf16(s[10], s[11]);
                u32 d0 = cvt_pk_bf16(s[12], s[13]);
                u32 d1 = cvt_pk_bf16(s[14], s[15]);
                permlane32_swap(c0, d0);
                permlane32_swap(c1, d1);
                u32x4 w2; w2.x = c0; w2.y = c1; w2.z = d0; w2.w = d1;
                pb[1] = __builtin_bit_cast(bf16x8, w2);
            }

            __builtin_amdgcn_s_setprio(1);
#pragma unroll
            for (int k2 = 0; k2 < 2; ++k2) {
                const int sg2 = c * 4 + k2 * 2 + hi;
                bf16x8 v0 = *reinterpret_cast<const bf16x8*>(
                    Vsb + l31 * 64 + ((sg2 ^ (l31 & 7)) * 8));
                accO0 = mfma32(v0, pb[k2], accO0);
                bf16x8 v1 = *reinterpret_cast<const bf16x8*>(
                    Vsb + (32 + l31) * 64 + ((sg2 ^ (l31 & 7)) * 8));
                accO1 = mfma32(v1, pb[k2], accO1);
            }
            __builtin_amdgcn_s_setprio(0);
        }
        __syncthreads();
    }

    lsum += __shfl_xor(lsum, 32);

    u16* Ob = (p ? pO1 : pO0) + ((size_t)bt * 128 + wave * 32 + l31) * 64;
#pragma unroll
    for (int t = 0; t < 4; ++t) {
        u32 p0 = cvt_pk_bf16(accO0[4 * t], accO0[4 * t + 1]);
        u32 p1 = cvt_pk_bf16(accO0[4 * t + 2], accO0[4 * t + 3]);
        *reinterpret_cast<uint2*>(Ob + t * 8 + 4 * hi) = make_uint2(p0, p1);
        u32 q0 = cvt_pk_bf16(accO1[4 * t], accO1[4 * t + 1]);
        u32 q1 = cvt_pk_bf16(accO1[4 * t + 2], accO1[4 * t + 3]);
        *reinterpret_cast<uint2*>(Ob + 32 + t * 8 + 4 * hi) = make_uint2(q0, q1);
    }
    if (hi == 0) pl[p * PLSTRIDE + bt * 128 + wave * 32 + l31] = lsum;
}

extern "C" void kernel_launch(void* const* d_in, const int* in_sizes, int n_in,
                              void* d_out, int out_size, void* d_ws, size_t ws_size,
                              hipStream_t stream) {
    const float* hs = (const float*)d_in[0];
    const float* qw = (const float*)d_in[1];
    const float* kw = (const float*)d_in[2];
    const float* vw = (const float*)d_in[3];
    const float* ow = (const float*)d_in[4];
    float* out = (float*)d_out;

    const size_t TSZ = (size_t)NHEADS * HEADSZ;
    const size_t WSZ = (size_t)HID * HID;
    u16* hsb = (u16*)d_ws;      // reused as pO0 after the QKV GEMM consumes hs
    u16* wqb = hsb + TSZ;       // wq|wk|wv|wo contiguous
    u16* wkb = wqb + WSZ;
    u16* wvb = wkb + WSZ;
    u16* wob = wvb + WSZ;
    u16* qb  = wob + WSZ;       // q|k|vt contiguous (from fused QKV gemm)
    u16* kb  = qb + TSZ;
    u16* vt  = kb + TSZ;
    u16* pO0 = hsb;
    u16* pO1 = vt + TSZ;
    float* pl = (float*)(pO1 + TSZ);

    CastJob cj;
    cj.src[0] = hs; cj.dst[0] = hsb; cj.n[0] = (int)TSZ;
    cj.src[1] = qw; cj.dst[1] = wqb; cj.n[1] = (int)WSZ;
    cj.src[2] = kw; cj.dst[2] = wkb; cj.n[2] = (int)WSZ;
    cj.src[3] = vw; cj.dst[3] = wvb; cj.n[3] = (int)WSZ;
    cj.src[4] = ow; cj.dst[4] = wob; cj.n[4] = (int)WSZ;
    cast_bf16<<<dim3(2304, 5), 256, 0, stream>>>(cj);

    // fused QKV projection (V written pre-transposed)
    gemm_mfma<0, 1, true, true><<<dim3(24, 36), 256, 0, stream>>>(hsb, wqb, qb, 0.125f * LOG2E);
    attn_mfma<<<NHEADS * NTILES * 2, 256, 0, stream>>>(qb, kb, vt, pO0, pO1, pl);
    // output projection with fused parity-merge + 1/l normalization
    gemm_out<<<dim3(8, 72), 256, 0, stream>>>(pO0, pO1, pl, wob, out);
}

// Round 6
// 158.717 us; speedup vs baseline: 1.2457x; 1.0323x over previous
//
#include <hip/hip_runtime.h>
#include <math.h>

#define HID 1024
#define NHEADS 16
#define NTILES 36
#define HEADSZ (36*128*64)
#define LOG2E 1.4426950408889634f
#define PLSTRIDE 73728   // 16*36*128

typedef unsigned short u16;
typedef unsigned int u32;
typedef __attribute__((ext_vector_type(8))) u16 ushort8v;
typedef __attribute__((ext_vector_type(8))) __bf16 bf16x8;
typedef __attribute__((ext_vector_type(16))) float f32x16;
typedef __attribute__((ext_vector_type(4))) u32 u32x4;

__device__ __forceinline__ u32 cvt_pk_bf16(float lo, float hi) {
  u32 r;
  asm("v_cvt_pk_bf16_f32 %0, %1, %2" : "=v"(r) : "v"(lo), "v"(hi));
  return r;
}
__device__ __forceinline__ void permlane32_swap(u32 &a, u32 &b) {
  asm volatile("v_permlane32_swap_b32 %0, %1" : "+v"(a), "+v"(b));
}
__device__ __forceinline__ void gld_lds16(const void* g, void* l) {
  __builtin_amdgcn_global_load_lds((const __attribute__((address_space(1))) u32*)g,
                                   (__attribute__((address_space(3))) u32*)l, 16, 0, 0);
}
__device__ __forceinline__ f32x16 mfma32(bf16x8 a, bf16x8 b, f32x16 c) {
  return __builtin_amdgcn_mfma_f32_32x32x16_bf16(a, b, c, 0, 0, 0);
}
__device__ __forceinline__ u16 bf16r(float x) {
  u32 b = __builtin_bit_cast(u32, x);
  b += 0x7fff + ((b >> 16) & 1);
  return (u16)(b >> 16);
}
__device__ __forceinline__ float bf2f(u16 v) {
  return __builtin_bit_cast(float, (u32)v << 16);
}

// ---------------- cast fp32 -> bf16 (5 arrays in one launch) ----------------
struct CastJob { const float* src[5]; u16* dst[5]; int n[5]; };

__global__ __launch_bounds__(256)
void cast_bf16(CastJob j) {
  const int w = blockIdx.y;
  const int n = j.n[w];
  const int i = (blockIdx.x * 256 + threadIdx.x) * 8;
  if (i >= n) return;
  const float4 v0 = *reinterpret_cast<const float4*>(j.src[w] + i);
  const float4 v1 = *reinterpret_cast<const float4*>(j.src[w] + i + 4);
  u32x4 o;
  o.x = cvt_pk_bf16(v0.x, v0.y);
  o.y = cvt_pk_bf16(v0.z, v0.w);
  o.z = cvt_pk_bf16(v1.x, v1.y);
  o.w = cvt_pk_bf16(v1.z, v1.w);
  *reinterpret_cast<u32x4*>(j.dst[w] + i) = o;
}

// ---------------- bf16 MFMA GEMM: C = A @ B^T ----------------
// M iterated in TILEIZED order (blockIdx.y = attention tile, 128 rows).
// AMODE 0: A bf16 row-major [4608][1024].  AMODE 1: A bf16 tileized.
// CMODE 0: C fp32 row-major.               CMODE 1: C bf16 tileized.
// QKV: B/C span q|k|v; heads >=32 (the V section) are written TRANSPOSED
//      ([head][tile][dh][within]) so no separate transpose pass is needed.
// DBUF: double-buffered LDS (64KB) vs single-buffer (32KB).
// NOTE (rounds 4-5): fusing the parity-merge into this GEMM's A-stage lost
// 5-8 us vs the separate merge_attn twice -> separate path is kept.
template<int AMODE, int CMODE, bool QKV, bool DBUF>
__global__ __launch_bounds__(256)
void gemm_mfma(const u16* __restrict__ A, const u16* __restrict__ B,
               void* __restrict__ Cv, float alpha)
{
    __shared__ __align__(16) u16 sm[DBUF ? 2 : 1][2][8192];

    const int tid = threadIdx.x;
    const int wv = tid >> 6, l = tid & 63;
    const int l31 = l & 31, hi = l >> 5;
    const int wm = wv >> 1, wn = wv & 1;
    const int by = blockIdx.y;
    const int n0 = blockIdx.x * 128;
    const float av = (QKV && n0 >= 1024) ? 1.0f : alpha;

    const int tt = by / 9, rem = by % 9, th = rem / 3, tw = rem % 3;
    const int tilebase = tt * 1152 + th * 192 + tw * 8;

    const int lrow = l >> 3;
    const int lslot = l & 7;
    const int sg = (lslot ^ lrow) * 8;
    const u16* aptr[4];
    const u16* bptr[4];
#pragma unroll
    for (int i = 0; i < 4; ++i) {
        const int row = (wv * 4 + i) * 8 + lrow;
        if (AMODE == 0) {
            const int s = tilebase + (row >> 6) * 576 + ((row >> 3) & 7) * 24 + (row & 7);
            aptr[i] = A + (size_t)s * HID + sg;
        } else {
            aptr[i] = A + (size_t)(by * 128 + row) * 64 + sg;
        }
        bptr[i] = B + (size_t)(n0 + row) * HID + sg;
    }

    auto stage = [&](int buf, int kc) {
#pragma unroll
        for (int i = 0; i < 4; ++i) {
            const u16* ga = (AMODE == 0) ? (aptr[i] + kc)
                                         : (aptr[i] + (size_t)(kc >> 6) * HEADSZ);
            gld_lds16(ga, &sm[buf][0][(wv * 4 + i) * 512]);
            gld_lds16(bptr[i] + kc, &sm[buf][1][(wv * 4 + i) * 512]);
        }
    };

    f32x16 acc[2][2];
#pragma unroll
    for (int mb = 0; mb < 2; ++mb)
#pragma unroll
        for (int nb = 0; nb < 2; ++nb)
#pragma unroll
            for (int i = 0; i < 16; ++i) acc[mb][nb][i] = 0.f;

    auto compute = [&](int buf) {
        __builtin_amdgcn_s_setprio(1);
#pragma unroll
        for (int kk = 0; kk < 4; ++kk) {
            bf16x8 af[2], bfr[2];
#pragma unroll
            for (int mb = 0; mb < 2; ++mb) {
                const int row = wm * 64 + mb * 32 + l31;
                af[mb] = *reinterpret_cast<const bf16x8*>(
                    &sm[buf][0][row * 64 + (((kk * 2 + hi) ^ (row & 7)) * 8)]);
            }
#pragma unroll
            for (int nb = 0; nb < 2; ++nb) {
                const int row = wn * 64 + nb * 32 + l31;
                bfr[nb] = *reinterpret_cast<const bf16x8*>(
                    &sm[buf][1][row * 64 + (((kk * 2 + hi) ^ (row & 7)) * 8)]);
            }
#pragma unroll
            for (int mb = 0; mb < 2; ++mb)
#pragma unroll
                for (int nb = 0; nb < 2; ++nb)
                    acc[mb][nb] = mfma32(af[mb], bfr[nb], acc[mb][nb]);
        }
        __builtin_amdgcn_s_setprio(0);
    };

    if (DBUF) {
        stage(0, 0);
        __syncthreads();
        int cur = 0;
        for (int kc = 0; kc < HID; kc += 64) {
            if (kc + 64 < HID) stage(cur ^ 1, kc + 64);
            compute(cur);
            __syncthreads();
            cur ^= 1;
        }
    } else {
        for (int kc = 0; kc < HID; kc += 64) {
            __syncthreads();
            stage(0, kc);
            __syncthreads();
            compute(0);
        }
    }

    if (CMODE == 0) {
        float* C = (float*)Cv;
#pragma unroll
        for (int mb = 0; mb < 2; ++mb)
#pragma unroll
            for (int r = 0; r < 16; ++r) {
                const int m = wm * 64 + mb * 32 + (r & 3) + 8 * (r >> 2) + 4 * hi;
                const int s = tilebase + (m >> 6) * 576 + ((m >> 3) & 7) * 24 + (m & 7);
#pragma unroll
                for (int nb = 0; nb < 2; ++nb) {
                    const int n = n0 + wn * 64 + nb * 32 + l31;
                    C[(size_t)s * HID + n] = acc[mb][nb][r] * av;
                }
            }
    } else {
        u16* C = (u16*)Cv;
#pragma unroll
        for (int mb = 0; mb < 2; ++mb)
#pragma unroll
            for (int rq = 0; rq < 4; ++rq) {
                const int mbase = wm * 64 + mb * 32 + 8 * rq + 4 * hi;
#pragma unroll
                for (int nb = 0; nb < 2; ++nb) {
                    const int n = n0 + wn * 64 + nb * 32 + l31;
                    const int head = n >> 6, dh = n & 63;
                    if (QKV && head >= 32) {
                        // V: write transposed [head][tile][dh][within]
                        u32 w0 = cvt_pk_bf16(acc[mb][nb][rq * 4 + 0], acc[mb][nb][rq * 4 + 1]);
                        u32 w1 = cvt_pk_bf16(acc[mb][nb][rq * 4 + 2], acc[mb][nb][rq * 4 + 3]);
                        *reinterpret_cast<uint2*>(C + (size_t)head * HEADSZ +
                            (size_t)by * 8192 + dh * 128 + mbase) = make_uint2(w0, w1);
                    } else {
#pragma unroll
                        for (int j = 0; j < 4; ++j) {
                            const int m = mbase + j;
                            C[(size_t)head * HEADSZ + (size_t)(by * 128 + m) * 64 + dh] =
                                bf16r(acc[mb][nb][rq * 4 + j] * av);
                        }
                    }
                }
            }
    }
}

// attention: 1152 blocks = (head, q-tile, key-parity); 4 waves x 32 q-rows.
// parity p handles the p-th 64-key half of each of the 27 neighbor tiles.
// Round-0 structure. No pipe is saturated (LDS-port ~69%, VALU 45%, MFMA 34%)
// -> latency-bound, residency-limited. Occupancy anomaly theory: VGPR_Count=48
// is ARCH-only; the compiler balloons unified usage via AGPR offload (~150/wave
// -> 3 waves/SIMD ~= measured 9/CU) while launch_bounds' waves/EU bound is
// honored on the arch side only. True minimum live set ~110 regs, so a 128-reg
// unified cap (4 waves/EU) should fit WITHOUT spill and lift residency 33%.
// This round's single attn variable: launch_bounds (256,5) -> (256,4).
// Spill check: WRITE_SIZE must stay 19008 KB.
// No-max softmax -> partials merge by pure addition in merge_attn.
// XCD-swizzled blockIdx: each XCD owns 2 heads (K/V fit its 4MB L2).
__global__ __launch_bounds__(256, 4)
void attn_mfma(const u16* __restrict__ Q, const u16* __restrict__ K,
               const u16* __restrict__ Vt, u16* __restrict__ pO0,
               u16* __restrict__ pO1, float* __restrict__ pl)
{
    __shared__ u16 sm[2][2][4096];   // [buf][K=0 / V=1][64 x 64] = 32 KB

    const int tid = threadIdx.x;
    const int wave = tid >> 6;
    const int lane = tid & 63;
    const int l31 = lane & 31;
    const int hi  = lane >> 5;

    // XCD-aware bijective swizzle: 1152 = 8 * 144
    const int logical = (blockIdx.x & 7) * 144 + (blockIdx.x >> 3);
    const int p  = logical & 1;
    const int bt = logical >> 1;       // head*36 + tile
    const int tl = bt % NTILES;
    const int hd = bt / NTILES;
    const size_t headbase = (size_t)hd * HEADSZ;

    const u16* Qg = Q + headbase + (size_t)tl * 8192;
    const u16* Kh = K + headbase;
    const u16* Vh = Vt + headbase;

    bf16x8 qf[4];
    {
        const u16* qrow = Qg + (wave * 32 + l31) * 64 + hi * 8;
#pragma unroll
        for (int ks = 0; ks < 4; ++ks)
            qf[ks] = *reinterpret_cast<const bf16x8*>(qrow + ks * 16);
    }

    const int base_t = (min(max(tl / 9, 1), 2) - 1) * 9;

    const int srow = lane >> 3;   // 0..7
    const int slot = lane & 7;

    auto stage = [&](int i, int bi) {
        const int kt = base_t + i;
        const u16* Kg = Kh + (size_t)kt * 8192 + p * 4096;
        const u16* Vg = Vh + (size_t)kt * 8192 + p * 64;
        u16* dk = &sm[bi][0][0];
        u16* dv = &sm[bi][1][0];
#pragma unroll
        for (int q = 0; q < 2; ++q) {
            const int seg = wave * 2 + q;
            const int key = seg * 8 + srow;
            gld_lds16(Kg + key * 64 + ((slot ^ (key & 7)) * 8), dk + seg * 512);
            const int dh = seg * 8 + srow;
            gld_lds16(Vg + dh * 128 + ((slot ^ (dh & 7)) * 8), dv + seg * 512);
        }
    };

    f32x16 accO0, accO1;
#pragma unroll
    for (int i = 0; i < 16; ++i) { accO0[i] = 0.f; accO1[i] = 0.f; }
    float lsum = 0.f;

    stage(0, 0);
    __syncthreads();

    for (int i = 0; i < 27; ++i) {
        const int cur = i & 1;
        if (i + 1 < 27) stage(i + 1, cur ^ 1);
        const u16* Ksb = &sm[cur][0][0];
        const u16* Vsb = &sm[cur][1][0];

#pragma unroll
        for (int c = 0; c < 2; ++c) {
            f32x16 s;
#pragma unroll
            for (int i2 = 0; i2 < 16; ++i2) s[i2] = 0.f;
            const int kr = c * 32 + l31;
            __builtin_amdgcn_s_setprio(1);
#pragma unroll
            for (int ks = 0; ks < 4; ++ks) {
                bf16x8 a = *reinterpret_cast<const bf16x8*>(
                    Ksb + kr * 64 + (((2 * ks + hi) ^ (kr & 7)) * 8));
                s = mfma32(a, qf[ks], s);
            }
            __builtin_amdgcn_s_setprio(0);

            // plain exp2 (scores pre-scaled by log2e/8 in Q; bounded, no max)
#pragma unroll
            for (int i2 = 0; i2 < 16; ++i2) s[i2] = __builtin_amdgcn_exp2f(s[i2]);

            float ps = 0.f;
#pragma unroll
            for (int i2 = 0; i2 < 16; ++i2) ps += s[i2];
            lsum += ps;

            // pack P -> 2 bf16 B-frags (32 keys)
            bf16x8 pb[2];
            {
                u32 a0 = cvt_pk_bf16(s[0], s[1]);
                u32 a1 = cvt_pk_bf16(s[2], s[3]);
                u32 b0 = cvt_pk_bf16(s[4], s[5]);
                u32 b1 = cvt_pk_bf16(s[6], s[7]);
                permlane32_swap(a0, b0);
                permlane32_swap(a1, b1);
                u32x4 w; w.x = a0; w.y = a1; w.z = b0; w.w = b1;
                pb[0] = __builtin_bit_cast(bf16x8, w);
                u32 c0 = cvt_pk_bf16(s[8], s[9]);
                u32 c1 = cvt_pk_bf16(s[10], s[11]);
                u32 d0 = cvt_pk_bf16(s[12], s[13]);
                u32 d1 = cvt_pk_bf16(s[14], s[15]);
                permlane32_swap(c0, d0);
                permlane32_swap(c1, d1);
                u32x4 w2; w2.x = c0; w2.y = c1; w2.z = d0; w2.w = d1;
                pb[1] = __builtin_bit_cast(bf16x8, w2);
            }

            __builtin_amdgcn_s_setprio(1);
#pragma unroll
            for (int k2 = 0; k2 < 2; ++k2) {
                const int sg2 = c * 4 + k2 * 2 + hi;
                bf16x8 v0 = *reinterpret_cast<const bf16x8*>(
                    Vsb + l31 * 64 + ((sg2 ^ (l31 & 7)) * 8));
                accO0 = mfma32(v0, pb[k2], accO0);
                bf16x8 v1 = *reinterpret_cast<const bf16x8*>(
                    Vsb + (32 + l31) * 64 + ((sg2 ^ (l31 & 7)) * 8));
                accO1 = mfma32(v1, pb[k2], accO1);
            }
            __builtin_amdgcn_s_setprio(0);
        }
        __syncthreads();
    }

    lsum += __shfl_xor(lsum, 32);

    u16* Ob = (p ? pO1 : pO0) + ((size_t)bt * 128 + wave * 32 + l31) * 64;
#pragma unroll
    for (int t = 0; t < 4; ++t) {
        u32 p0 = cvt_pk_bf16(accO0[4 * t], accO0[4 * t + 1]);
        u32 p1 = cvt_pk_bf16(accO0[4 * t + 2], accO0[4 * t + 3]);
        *reinterpret_cast<uint2*>(Ob + t * 8 + 4 * hi) = make_uint2(p0, p1);
        u32 q0 = cvt_pk_bf16(accO1[4 * t], accO1[4 * t + 1]);
        u32 q1 = cvt_pk_bf16(accO1[4 * t + 2], accO1[4 * t + 3]);
        *reinterpret_cast<uint2*>(Ob + 32 + t * 8 + 4 * hi) = make_uint2(q0, q1);
    }
    if (hi == 0) pl[p * PLSTRIDE + bt * 128 + wave * 32 + l31] = lsum;
}

// merge the two key-parity partials: O = (pO0 + pO1) / (l0 + l1), bf16 tileized
__global__ __launch_bounds__(256)
void merge_attn(const u16* __restrict__ pO0, const u16* __restrict__ pO1,
                const float* __restrict__ pl, u16* __restrict__ O)
{
    const int b = blockIdx.x;          // head*36 + tile
    const int tid = threadIdx.x;
    const int row = tid >> 1;
    const int d0 = (tid & 1) * 32;
    const size_t rbase = ((size_t)b * 128 + row) * 64 + d0;
    const float inv = 1.f / (pl[b * 128 + row] + pl[PLSTRIDE + b * 128 + row]);
#pragma unroll
    for (int g = 0; g < 4; ++g) {
        ushort8v a = *reinterpret_cast<const ushort8v*>(pO0 + rbase + g * 8);
        ushort8v c = *reinterpret_cast<const ushort8v*>(pO1 + rbase + g * 8);
        u32 w[4];
#pragma unroll
        for (int h = 0; h < 4; ++h) {
            float f0 = (bf2f(a[2 * h])     + bf2f(c[2 * h]))     * inv;
            float f1 = (bf2f(a[2 * h + 1]) + bf2f(c[2 * h + 1])) * inv;
            w[h] = cvt_pk_bf16(f0, f1);
        }
        u32x4 st; st.x = w[0]; st.y = w[1]; st.z = w[2]; st.w = w[3];
        *reinterpret_cast<u32x4*>(O + rbase + g * 8) = st;
    }
}

extern "C" void kernel_launch(void* const* d_in, const int* in_sizes, int n_in,
                              void* d_out, int out_size, void* d_ws, size_t ws_size,
                              hipStream_t stream) {
    const float* hs = (const float*)d_in[0];
    const float* qw = (const float*)d_in[1];
    const float* kw = (const float*)d_in[2];
    const float* vw = (const float*)d_in[3];
    const float* ow = (const float*)d_in[4];
    float* out = (float*)d_out;

    const size_t TSZ = (size_t)NHEADS * HEADSZ;
    const size_t WSZ = (size_t)HID * HID;
    u16* hsb = (u16*)d_ws;      // reused as pO0 after the QKV GEMM consumes hs
    u16* wqb = hsb + TSZ;       // wq|wk|wv|wo contiguous
    u16* wkb = wqb + WSZ;
    u16* wvb = wkb + WSZ;
    u16* wob = wvb + WSZ;
    u16* qb  = wob + WSZ;       // q|k|vt contiguous (from fused QKV gemm)
    u16* kb  = qb + TSZ;
    u16* vt  = kb + TSZ;
    u16* pO0 = hsb;
    u16* pO1 = vt + TSZ;
    float* pl = (float*)(pO1 + TSZ);
    u16* aob = (u16*)(pl + 2 * PLSTRIDE);

    CastJob cj;
    cj.src[0] = hs; cj.dst[0] = hsb; cj.n[0] = (int)TSZ;
    cj.src[1] = qw; cj.dst[1] = wqb; cj.n[1] = (int)WSZ;
    cj.src[2] = kw; cj.dst[2] = wkb; cj.n[2] = (int)WSZ;
    cj.src[3] = vw; cj.dst[3] = wvb; cj.n[3] = (int)WSZ;
    cj.src[4] = ow; cj.dst[4] = wob; cj.n[4] = (int)WSZ;
    cast_bf16<<<dim3(2304, 5), 256, 0, stream>>>(cj);

    // fused QKV projection (V written pre-transposed)
    gemm_mfma<0, 1, true, true><<<dim3(24, 36), 256, 0, stream>>>(hsb, wqb, qb, 0.125f * LOG2E);
    attn_mfma<<<NHEADS * NTILES * 2, 256, 0, stream>>>(qb, kb, vt, pO0, pO1, pl);
    merge_attn<<<NHEADS * NTILES, 256, 0, stream>>>(pO0, pO1, pl, aob);
    gemm_mfma<1, 0, false, true><<<dim3(8, 36), 256, 0, stream>>>(aob, wob, out, 1.0f);
}